// Round 2
// baseline (41048.544 us; speedup 1.0000x reference)
//
#include <hip/hip_runtime.h>
#include <hip/hip_bf16.h>

#define H 128

typedef __hip_bfloat16 bf16;
typedef __hip_bfloat162 bf162;

__device__ __forceinline__ int lb(const int* __restrict__ a, int n, int v) {
  int lo = 0, hi = n;
  while (lo < hi) { int m = (lo + hi) >> 1; if (a[m] < v) lo = m + 1; else hi = m; }
  return lo;
}

__device__ __forceinline__ float wave_sum(float v) {
#pragma unroll
  for (int off = 32; off > 0; off >>= 1) v += __shfl_xor(v, off);
  return v;
}
__device__ __forceinline__ float wave_max(float v) {
#pragma unroll
  for (int off = 32; off > 0; off >>= 1) v = fmaxf(v, __shfl_xor(v, off));
  return v;
}

// out[c] += sum_k z[k] * W[k*H + c] for the two columns (2*lane, 2*lane+1) this lane owns.
// z is distributed: lane l holds cols 2l (z0) and 2l+1 (z1). Broadcast via shfl.
__device__ __forceinline__ void matvec128(float z0, float z1, const float* __restrict__ Wlds,
                                          int lane, float& m0, float& m1) {
#pragma unroll
  for (int k = 0; k < H; ++k) {
    float s = __shfl((k & 1) ? z1 : z0, k >> 1);
    float2 w = *(const float2*)(Wlds + k * H + 2 * lane);
    m0 = fmaf(s, w.x, m0);
    m1 = fmaf(s, w.y, m1);
  }
}

// ---------------- CSR build ----------------
__global__ void k_count(const int* __restrict__ dst, int* __restrict__ cnt, int E) {
  int i = blockIdx.x * blockDim.x + threadIdx.x;
  if (i < E) atomicAdd(cnt + dst[i], 1);
}

__global__ void k_scan(const int* __restrict__ cnt, int* __restrict__ off,
                       int* __restrict__ cur, int N) {
  __shared__ int part[1024];
  int t = threadIdx.x;
  int C = (N + 1023) / 1024;
  int beg = t * C, end = min(beg + C, N);
  int s = 0;
  for (int i = beg; i < end; ++i) s += cnt[i];
  part[t] = s;
  __syncthreads();
  for (int d = 1; d < 1024; d <<= 1) {
    int v = (t >= d) ? part[t - d] : 0;
    __syncthreads();
    part[t] += v;
    __syncthreads();
  }
  int run = (t == 0) ? 0 : part[t - 1];
  for (int i = beg; i < end; ++i) {
    off[i] = run; cur[i] = run;
    run += cnt[i];
  }
  if (t == 1023) off[N] = part[1023];
}

__global__ void k_scatter(const int* __restrict__ dst, int* __restrict__ cur,
                          int* __restrict__ eids, int E) {
  int i = blockIdx.x * blockDim.x + threadIdx.x;
  if (i < E) { int p = atomicAdd(cur + dst[i], 1); eids[p] = i; }
}

// ---------------- z2 = relu(bn2(relu(bn1(segsum)) @ Wz + bz)) ----------------
__global__ void k_z(const int* __restrict__ pos_index, const float* __restrict__ pos_enc,
                    const int* __restrict__ pos_batch, const float* __restrict__ z_table,
                    const float* __restrict__ bn1_g, const float* __restrict__ bn1_b,
                    const float* __restrict__ Wz, const float* __restrict__ bz,
                    const float* __restrict__ bn2_g, const float* __restrict__ bn2_b,
                    bf16* __restrict__ z2, int E, int P) {
  __shared__ float Wlds[H * H];
  for (int i = threadIdx.x; i < H * H; i += blockDim.x) Wlds[i] = Wz[i];
  __syncthreads();
  const int lane = threadIdx.x & 63;
  const int wid = (blockIdx.x * blockDim.x + threadIdx.x) >> 6;
  const int nw = (gridDim.x * blockDim.x) >> 6;
  const float inv = rsqrtf(1.0f + 1e-5f);
  const int c0 = 2 * lane, c1 = 2 * lane + 1;
  const float g10 = bn1_g[c0] * inv, g11 = bn1_g[c1] * inv;
  const float b10 = bn1_b[c0], b11 = bn1_b[c1];
  const float g20 = bn2_g[c0] * inv, g21 = bn2_g[c1] * inv;
  const float b20 = bn2_b[c0], b21 = bn2_b[c1];
  const float bz0 = bz[c0], bz1 = bz[c1];
  for (int e = wid; e < E; e += nw) {
    int lo = lb(pos_batch, P, e), hi = lb(pos_batch, P, e + 1);
    float a0 = 0.f, a1 = 0.f;
    for (int p = lo; p < hi; ++p) {
      int r = pos_index[p];
      float w = pos_enc[p];
      float2 zr = *(const float2*)(z_table + (size_t)r * H + c0);
      a0 = fmaf(w, zr.x, a0);
      a1 = fmaf(w, zr.y, a1);
    }
    float z0 = fmaxf(0.f, fmaf(a0, g10, b10));
    float z1 = fmaxf(0.f, fmaf(a1, g11, b11));
    float m0 = 0.f, m1 = 0.f;
    matvec128(z0, z1, Wlds, lane, m0, m1);
    float y0 = fmaxf(0.f, fmaf(m0 + bz0, g20, b20));
    float y1 = fmaxf(0.f, fmaf(m1 + bz1, g21, b21));
    bf162 o;
    o.x = __float2bfloat16(y0);
    o.y = __float2bfloat16(y1);
    *(bf162*)(z2 + (size_t)e * H + c0) = o;
  }
}

// ---------------- conv1: h1[dst] += relu(1 + z2.We1 + be1) ----------------
__global__ void k_msg1(const bf16* __restrict__ z2, const float* __restrict__ We1,
                       const float* __restrict__ be1, const int* __restrict__ dst,
                       float* __restrict__ h1, int E) {
  const int lane = threadIdx.x & 63;
  const int wid = (blockIdx.x * blockDim.x + threadIdx.x) >> 6;
  const int nw = (gridDim.x * blockDim.x) >> 6;
  float2 w = *(const float2*)(We1 + 2 * lane);
  float be = be1[0];
  for (int e = wid; e < E; e += nw) {
    bf162 zp = *(const bf162*)(z2 + (size_t)e * H + 2 * lane);
    float d = __bfloat162float(zp.x) * w.x + __bfloat162float(zp.y) * w.y;
    d = wave_sum(d);
    if (lane == 0) atomicAdd(h1 + dst[e], fmaxf(0.f, 1.0f + d + be));
  }
}

// ---------------- conv1 node MLP: x = relu(relu((1+h1)*W1a + b1a) @ W1b + b1b) ----------------
__global__ void k_c1mlp(const float* __restrict__ h1, const float* __restrict__ W1a,
                        const float* __restrict__ b1a, const float* __restrict__ W1b,
                        const float* __restrict__ b1b, float* __restrict__ x, int N) {
  __shared__ float Wlds[H * H];
  for (int i = threadIdx.x; i < H * H; i += blockDim.x) Wlds[i] = W1b[i];
  __syncthreads();
  const int lane = threadIdx.x & 63;
  const int wid = (blockIdx.x * blockDim.x + threadIdx.x) >> 6;
  const int nw = (gridDim.x * blockDim.x) >> 6;
  const int c0 = 2 * lane, c1 = c0 + 1;
  const float wa0 = W1a[c0], wa1 = W1a[c1];
  const float ba0 = b1a[c0], ba1 = b1a[c1];
  const float bb0 = b1b[c0], bb1 = b1b[c1];
  for (int n = wid; n < N; n += nw) {
    float hv = 1.0f + h1[n];
    float t0 = fmaxf(0.f, fmaf(hv, wa0, ba0));
    float t1 = fmaxf(0.f, fmaf(hv, wa1, ba1));
    float m0 = bb0, m1 = bb1;
    matvec128(t0, t1, Wlds, lane, m0, m1);
    float2 o = make_float2(fmaxf(0.f, m0), fmaxf(0.f, m1));
    *(float2*)(x + (size_t)n * H + c0) = o;
  }
}

// ---------------- GINE aggregation: h[n] = x[n] + sum_e relu(x[src] + z2[e]@We + be) ----------------
__global__ void k_agg(const float* __restrict__ x, const bf16* __restrict__ z2,
                      const float* __restrict__ We, const float* __restrict__ be,
                      const int* __restrict__ off, const int* __restrict__ eids,
                      const int* __restrict__ src, float* __restrict__ h, int N) {
  __shared__ float Wlds[H * H];
  for (int i = threadIdx.x; i < H * H; i += blockDim.x) Wlds[i] = We[i];
  __syncthreads();
  const int lane = threadIdx.x & 63;
  const int wid = (blockIdx.x * blockDim.x + threadIdx.x) >> 6;
  const int nw = (gridDim.x * blockDim.x) >> 6;
  const int c0 = 2 * lane, c1 = c0 + 1;
  const float be0 = be[c0], be1 = be[c1];
  for (int n = wid; n < N; n += nw) {
    float2 acc = *(const float2*)(x + (size_t)n * H + c0);
    int s0 = off[n], s1 = off[n + 1];
    for (int ei = s0; ei < s1; ++ei) {
      int e = eids[ei];
      int sn = src[e];
      bf162 zp = *(const bf162*)(z2 + (size_t)e * H + c0);
      float z0 = __bfloat162float(zp.x), z1 = __bfloat162float(zp.y);
      float m0 = be0, m1 = be1;
      matvec128(z0, z1, Wlds, lane, m0, m1);
      float2 xs = *(const float2*)(x + (size_t)sn * H + c0);
      acc.x += fmaxf(0.f, xs.x + m0);
      acc.y += fmaxf(0.f, xs.y + m1);
    }
    *(float2*)(h + (size_t)n * H + c0) = acc;
  }
}

// ---------------- generic row MLP: out[r] = relu(in[r] @ W + b)  (in==out is safe) -------------
__global__ void k_mlp(const float* __restrict__ in, const float* __restrict__ W,
                      const float* __restrict__ b, float* __restrict__ out, int R) {
  __shared__ float Wlds[H * H];
  for (int i = threadIdx.x; i < H * H; i += blockDim.x) Wlds[i] = W[i];
  __syncthreads();
  const int lane = threadIdx.x & 63;
  const int wid = (blockIdx.x * blockDim.x + threadIdx.x) >> 6;
  const int nw = (gridDim.x * blockDim.x) >> 6;
  const int c0 = 2 * lane, c1 = c0 + 1;
  const float b0 = b[c0], b1 = b[c1];
  for (int r = wid; r < R; r += nw) {
    float2 v = *(const float2*)(in + (size_t)r * H + c0);  // full row in regs before write
    float m0 = b0, m1 = b1;
    matvec128(v.x, v.y, Wlds, lane, m0, m1);
    float2 o = make_float2(fmaxf(0.f, m0), fmaxf(0.f, m1));
    *(float2*)(out + (size_t)r * H + c0) = o;
  }
}

// ---------------- pool: g[gi] = sum_{batch[n]==gi} x[n] ----------------
__global__ void k_pool(const float* __restrict__ x, const int* __restrict__ batch,
                       float* __restrict__ g, int N, int G) {
  __shared__ float red[4][H];
  int gi = blockIdx.x;
  int lane = threadIdx.x & 63;
  int w = threadIdx.x >> 6;
  int lo = lb(batch, N, gi), hi = lb(batch, N, gi + 1);
  float a0 = 0.f, a1 = 0.f;
  for (int n = lo + w; n < hi; n += 4) {
    float2 xv = *(const float2*)(x + (size_t)n * H + 2 * lane);
    a0 += xv.x;
    a1 += xv.y;
  }
  red[w][2 * lane] = a0;
  red[w][2 * lane + 1] = a1;
  __syncthreads();
  if (w == 0) {
    a0 = red[0][2 * lane] + red[1][2 * lane] + red[2][2 * lane] + red[3][2 * lane];
    a1 = red[0][2 * lane + 1] + red[1][2 * lane + 1] + red[2][2 * lane + 1] + red[3][2 * lane + 1];
    *(float2*)(g + (size_t)gi * H + 2 * lane) = make_float2(a0, a1);
  }
}

// ---------------- head: out = log_softmax(relu(g@Wl1+bl1) @ Wl2 + bl2) ----------------
__global__ void k_head(const float* __restrict__ g, const float* __restrict__ Wl1,
                       const float* __restrict__ bl1, const float* __restrict__ Wl2,
                       const float* __restrict__ bl2, float* __restrict__ out, int G) {
  int gi = blockIdx.x;
  int lane = threadIdx.x & 63;
  const int c0 = 2 * lane, c1 = c0 + 1;
  float2 gv = *(const float2*)(g + (size_t)gi * H + c0);
  float m0 = bl1[c0], m1 = bl1[c1];
#pragma unroll
  for (int k = 0; k < H; ++k) {
    float s = __shfl((k & 1) ? gv.y : gv.x, k >> 1);
    float2 w = *(const float2*)(Wl1 + k * H + c0);
    m0 = fmaf(s, w.x, m0);
    m1 = fmaf(s, w.y, m1);
  }
  float t0 = fmaxf(0.f, m0), t1 = fmaxf(0.f, m1);
  float L0 = bl2[c0], L1 = bl2[c1];
#pragma unroll
  for (int k = 0; k < H; ++k) {
    float s = __shfl((k & 1) ? t1 : t0, k >> 1);
    float2 w = *(const float2*)(Wl2 + k * H + c0);
    L0 = fmaf(s, w.x, L0);
    L1 = fmaf(s, w.y, L1);
  }
  float mx = wave_max(fmaxf(L0, L1));
  float sm = wave_sum(expf(L0 - mx) + expf(L1 - mx));
  float lse = mx + logf(sm);
  *(float2*)(out + (size_t)gi * H + c0) = make_float2(L0 - lse, L1 - lse);
}

__global__ void k_zero_out(float* __restrict__ out, int n) {
  int i = blockIdx.x * blockDim.x + threadIdx.x;
  if (i < n) out[i] = 0.f;
}

extern "C" void kernel_launch(void* const* d_in, const int* in_sizes, int n_in,
                              void* d_out, int out_size, void* d_ws, size_t ws_size,
                              hipStream_t stream) {
  const int* edge_index = (const int*)d_in[0];
  const int* batch = (const int*)d_in[1];
  const int* pos_index = (const int*)d_in[2];
  const float* pos_enc = (const float*)d_in[3];
  const int* pos_batch = (const int*)d_in[4];
  const float* z_table = (const float*)d_in[5];
  const float* bn1_g = (const float*)d_in[6];
  const float* bn1_b = (const float*)d_in[7];
  const float* Wz = (const float*)d_in[8];
  const float* bz = (const float*)d_in[9];
  const float* bn2_g = (const float*)d_in[10];
  const float* bn2_b = (const float*)d_in[11];
  const float* We1 = (const float*)d_in[12];
  const float* be1 = (const float*)d_in[13];
  const float* W1a = (const float*)d_in[14];
  const float* b1a = (const float*)d_in[15];
  const float* W1b = (const float*)d_in[16];
  const float* b1b = (const float*)d_in[17];
  const float* We = (const float*)d_in[18];
  const float* be = (const float*)d_in[19];
  const float* Wa = (const float*)d_in[20];
  const float* ba = (const float*)d_in[21];
  const float* Wb = (const float*)d_in[22];
  const float* bb = (const float*)d_in[23];
  const float* Wl1 = (const float*)d_in[24];
  const float* bl1 = (const float*)d_in[25];
  const float* Wl2 = (const float*)d_in[26];
  const float* bl2 = (const float*)d_in[27];

  const int E = in_sizes[0] / 2;
  const int N = in_sizes[1];
  const int P = in_sizes[2];
  const int L = in_sizes[18] / (H * H);
  const int G = out_size / H;
  const int* src = edge_index;
  const int* dst = edge_index + E;

  char* wsb = (char*)d_ws;
  size_t o = 0;
  auto alloc = [&](size_t bytes) -> void* {
    o = (o + 255) & ~(size_t)255;
    void* p = wsb + o;
    o += bytes;
    return p;
  };
  bf16* z2 = (bf16*)alloc((size_t)E * H * sizeof(bf16));  // 204.8 MB
  float* x = (float*)alloc((size_t)N * H * 4);            // 25.6 MB
  float* h = (float*)alloc((size_t)N * H * 4);            // 25.6 MB (also serves as 't')
  float* h1 = (float*)alloc((size_t)N * 4);
  int* cnt = (int*)alloc((size_t)N * 4);
  int* off = (int*)alloc((size_t)(N + 1) * 4);
  int* cur = (int*)alloc((size_t)N * 4);
  int* eids = (int*)alloc((size_t)E * 4);
  float* g = (float*)alloc((size_t)G * H * 4);
  (void)n_in;

  // Fail fast (clean absmax failure instead of an OOB queue hang) if ws is too small.
  if (o > ws_size) {
    k_zero_out<<<(out_size + 255) / 256, 256, 0, stream>>>((float*)d_out, out_size);
    return;
  }

  hipMemsetAsync(cnt, 0, (size_t)N * 4, stream);
  hipMemsetAsync(h1, 0, (size_t)N * 4, stream);

  k_count<<<(E + 255) / 256, 256, 0, stream>>>(dst, cnt, E);
  k_scan<<<1, 1024, 0, stream>>>(cnt, off, cur, N);
  k_scatter<<<(E + 255) / 256, 256, 0, stream>>>(dst, cur, eids, E);

  k_z<<<1024, 512, 0, stream>>>(pos_index, pos_enc, pos_batch, z_table, bn1_g, bn1_b, Wz, bz,
                                bn2_g, bn2_b, z2, E, P);
  k_msg1<<<2048, 256, 0, stream>>>(z2, We1, be1, dst, h1, E);
  k_c1mlp<<<512, 512, 0, stream>>>(h1, W1a, b1a, W1b, b1b, x, N);

  for (int l = 0; l < L; ++l) {
    k_agg<<<1024, 512, 0, stream>>>(x, z2, We + (size_t)l * H * H, be + (size_t)l * H, off, eids,
                                    src, h, N);
    k_mlp<<<512, 512, 0, stream>>>(h, Wa + (size_t)l * H * H, ba + (size_t)l * H, h, N);
    k_mlp<<<512, 512, 0, stream>>>(h, Wb + (size_t)l * H * H, bb + (size_t)l * H, x, N);
  }

  k_pool<<<G, 256, 0, stream>>>(x, batch, g, N, G);
  k_head<<<G, 64, 0, stream>>>(g, Wl1, bl1, Wl2, bl2, (float*)d_out, G);
}

// Round 3
// 2384.040 us; speedup vs baseline: 17.2181x; 17.2181x over previous
//
#include <hip/hip_runtime.h>
#include <hip/hip_bf16.h>

#define H 128

typedef __attribute__((ext_vector_type(8))) short bf16x8;  // 8 bf16 = 4 VGPR
typedef __attribute__((ext_vector_type(4))) float f32x4;

__device__ __forceinline__ float bf2f(unsigned int u16) {
  union { float f; unsigned int i; } v;
  v.i = u16 << 16;
  return v.f;
}
__device__ __forceinline__ unsigned short f2bf(float f) {
  union { float f; unsigned int i; } v;
  v.f = f;
  unsigned int lsb = (v.i >> 16) & 1u;
  v.i += 0x7fffu + lsb;  // RNE
  return (unsigned short)(v.i >> 16);
}

__device__ __forceinline__ int lb(const int* __restrict__ a, int n, int v) {
  int lo = 0, hi = n;
  while (lo < hi) { int m = (lo + hi) >> 1; if (a[m] < v) lo = m + 1; else hi = m; }
  return lo;
}

__device__ __forceinline__ float wave_sum(float v) {
#pragma unroll
  for (int off = 32; off > 0; off >>= 1) v += __shfl_xor(v, off);
  return v;
}
__device__ __forceinline__ float wave_max(float v) {
#pragma unroll
  for (int off = 32; off > 0; off >>= 1) v = fmaxf(v, __shfl_xor(v, off));
  return v;
}

// Stage W (f32 [128][128], row=k, col=c) into LDS as MFMA B-fragments, fragment-linear:
// entry e = (ct*4+kc)*64+lane holds the bf16x8 lane `lane` needs for col-tile ct, k-chunk kc.
// B frag layout (16x16x32): lane holds B[k = kc*32 + 8*(lane>>4) + j][col = ct*16 + (lane&15)].
__device__ __forceinline__ void stage_B(const float* __restrict__ W, short* __restrict__ lds) {
  for (int e = threadIdx.x; e < 8 * 4 * 64; e += blockDim.x) {
    int lane = e & 63;
    int kc = (e >> 6) & 3;
    int ct = e >> 8;
    int col = ct * 16 + (lane & 15);
    int k0 = kc * 32 + (lane >> 4) * 8;
    bf16x8 pack;
#pragma unroll
    for (int j = 0; j < 8; ++j) pack[j] = (short)f2bf(W[(k0 + j) * H + col]);
    *(bf16x8*)(lds + (size_t)e * 8) = pack;
  }
}

// ---------------- CSR build ----------------
__global__ void k_count(const int* __restrict__ dst, int* __restrict__ cnt, int E) {
  int i = blockIdx.x * blockDim.x + threadIdx.x;
  if (i < E) atomicAdd(cnt + dst[i], 1);
}

__global__ void k_scan(const int* __restrict__ cnt, int* __restrict__ off,
                       int* __restrict__ cur, int N) {
  __shared__ int part[1024];
  int t = threadIdx.x;
  int C = (N + 1023) / 1024;
  int beg = t * C, end = min(beg + C, N);
  int s = 0;
  for (int i = beg; i < end; ++i) s += cnt[i];
  part[t] = s;
  __syncthreads();
  for (int d = 1; d < 1024; d <<= 1) {
    int v = (t >= d) ? part[t - d] : 0;
    __syncthreads();
    part[t] += v;
    __syncthreads();
  }
  int run = (t == 0) ? 0 : part[t - 1];
  for (int i = beg; i < end; ++i) {
    off[i] = run; cur[i] = run;
    run += cnt[i];
  }
  if (t == 1023) off[N] = part[1023];
}

__global__ void k_scatter(const int* __restrict__ dst, int* __restrict__ cur,
                          int* __restrict__ eids, int E) {
  int i = blockIdx.x * blockDim.x + threadIdx.x;
  if (i < E) { int p = atomicAdd(cur + dst[i], 1); eids[p] = i; }
}

__global__ void k_dstp(const int* __restrict__ off, int* __restrict__ dstp, int N) {
  int n = blockIdx.x * blockDim.x + threadIdx.x;
  if (n < N) {
    int lo = off[n], hi = off[n + 1];
    for (int i = lo; i < hi; ++i) dstp[i] = n;
  }
}

// in-place: eids[i] -> src[eids[i]]
__global__ void k_srcp(const int* __restrict__ src, int* __restrict__ e2s, int E) {
  int i = blockIdx.x * blockDim.x + threadIdx.x;
  if (i < E) e2s[i] = src[e2s[i]];
}

// pos_off[e] = first p with pos_batch[p] >= e
__global__ void k_posoff(const int* __restrict__ pos_batch, int* __restrict__ pos_off,
                         int P, int E) {
  int p = blockIdx.x * blockDim.x + threadIdx.x;
  if (p >= P) return;
  int b = pos_batch[p];
  int prev = (p == 0) ? -1 : pos_batch[p - 1];
  for (int q = prev + 1; q <= b; ++q) pos_off[q] = p;
  if (p == P - 1)
    for (int q = b + 1; q <= E; ++q) pos_off[q] = P;
}

// ---------------- za = relu(bn1(segsum)) -> z2p (CSR-permuted, bf16) ----------------
__global__ void k_za(const int* __restrict__ eids, const int* __restrict__ pos_off,
                     const int* __restrict__ pos_index, const float* __restrict__ pos_enc,
                     const float* __restrict__ z_table, const float* __restrict__ bn1_g,
                     const float* __restrict__ bn1_b, unsigned short* __restrict__ z2p, int E) {
  const int lane = threadIdx.x & 63;
  const int wid = (blockIdx.x * blockDim.x + threadIdx.x) >> 6;
  const int nw = (gridDim.x * blockDim.x) >> 6;
  const float inv = rsqrtf(1.0f + 1e-5f);
  const int c0 = lane * 2;
  const float g0 = bn1_g[c0] * inv, g1 = bn1_g[c0 + 1] * inv;
  const float b0 = bn1_b[c0], b1 = bn1_b[c0 + 1];
  for (int ei = wid; ei < E; ei += nw) {
    int e = eids[ei];
    int lo = pos_off[e], hi = pos_off[e + 1];
    float a0 = 0.f, a1 = 0.f;
    for (int p = lo; p < hi; ++p) {
      int r = pos_index[p];
      float w = pos_enc[p];
      float2 zr = *(const float2*)(z_table + (size_t)r * H + c0);
      a0 = fmaf(w, zr.x, a0);
      a1 = fmaf(w, zr.y, a1);
    }
    float y0 = fmaxf(0.f, fmaf(a0, g0, b0));
    float y1 = fmaxf(0.f, fmaf(a1, g1, b1));
    unsigned int pack = ((unsigned int)f2bf(y1) << 16) | f2bf(y0);
    *(unsigned int*)(z2p + (size_t)ei * H + c0) = pack;
  }
}

// ---------------- generic MFMA GEMM over 128 cols, K=128: out = epi(in @ W + bias) -------------
// Rows R must be a multiple of 16 (E=800000, N=50000 both are).
// In-place safe: each tile's 16 rows are fully loaded to registers before any store.
template <int IN_BF16, int BN, int OUT_BF16>
__global__ void k_gemm(const void* __restrict__ in, void* __restrict__ out,
                       const float* __restrict__ W, const float* __restrict__ bias,
                       const float* __restrict__ bng, const float* __restrict__ bnb, int R) {
  __shared__ short Blds[8 * 4 * 64 * 8];  // 32 KiB
  stage_B(W, Blds);
  __syncthreads();
  const int lane = threadIdx.x & 63;
  const int wv = threadIdx.x >> 6;
  const int tiles = R >> 4;
  const int nw = (gridDim.x * blockDim.x) >> 6;
  const float inv = rsqrtf(1.0f + 1e-5f);
  for (int t = blockIdx.x * (blockDim.x >> 6) + wv; t < tiles; t += nw) {
    const int arow = (t << 4) + (lane & 15);
    bf16x8 a[4];
    if (IN_BF16) {
      const short* ib = (const short*)in;
#pragma unroll
      for (int kc = 0; kc < 4; ++kc)
        a[kc] = *(const bf16x8*)(ib + (size_t)arow * H + kc * 32 + (lane >> 4) * 8);
    } else {
      const float* iff = (const float*)in;
#pragma unroll
      for (int kc = 0; kc < 4; ++kc) {
        const float* p = iff + (size_t)arow * H + kc * 32 + (lane >> 4) * 8;
#pragma unroll
        for (int j = 0; j < 8; ++j) a[kc][j] = (short)f2bf(p[j]);
      }
    }
    f32x4 acc[8];
#pragma unroll
    for (int ct = 0; ct < 8; ++ct) acc[ct] = (f32x4){0.f, 0.f, 0.f, 0.f};
#pragma unroll
    for (int ct = 0; ct < 8; ++ct)
#pragma unroll
      for (int kc = 0; kc < 4; ++kc) {
        bf16x8 b = *(const bf16x8*)(Blds + ((size_t)((ct << 2) + kc) * 64 + lane) * 8);
        acc[ct] = __builtin_amdgcn_mfma_f32_16x16x32_bf16(a[kc], b, acc[ct], 0, 0, 0);
      }
    const int r0 = (t << 4) + ((lane >> 4) << 2);
    const int cb = lane & 15;
#pragma unroll
    for (int ct = 0; ct < 8; ++ct) {
      int c = (ct << 4) + cb;
      float bv = bias[c];
      float gv = 0.f, b2 = 0.f;
      if (BN) { gv = bng[c] * inv; b2 = bnb[c]; }
#pragma unroll
      for (int j = 0; j < 4; ++j) {
        float y = acc[ct][j] + bv;
        if (BN) y = fmaf(y, gv, b2);
        y = fmaxf(y, 0.f);
        size_t idx = (size_t)(r0 + j) * H + c;
        if (OUT_BF16) ((unsigned short*)out)[idx] = f2bf(y);
        else ((float*)out)[idx] = y;
      }
    }
  }
}

// ---------------- fused GINE aggregation: h[dst] += relu(x[src] + z2p@We + be) ----------------
__global__ void k_agg_mfma(const unsigned short* __restrict__ x,
                           const unsigned short* __restrict__ z2p,
                           const float* __restrict__ We, const float* __restrict__ be,
                           const int* __restrict__ srcp, const int* __restrict__ dstp,
                           float* __restrict__ h, int E) {
  __shared__ short Blds[8 * 4 * 64 * 8];
  stage_B(We, Blds);
  __syncthreads();
  const int lane = threadIdx.x & 63;
  const int wv = threadIdx.x >> 6;
  const int tiles = E >> 4;
  const int nw = (gridDim.x * blockDim.x) >> 6;
  for (int t = blockIdx.x * (blockDim.x >> 6) + wv; t < tiles; t += nw) {
    const int arow = (t << 4) + (lane & 15);
    bf16x8 a[4];
#pragma unroll
    for (int kc = 0; kc < 4; ++kc)
      a[kc] = *(const bf16x8*)((const short*)z2p + (size_t)arow * H + kc * 32 + (lane >> 4) * 8);
    f32x4 acc[8];
#pragma unroll
    for (int ct = 0; ct < 8; ++ct) acc[ct] = (f32x4){0.f, 0.f, 0.f, 0.f};
#pragma unroll
    for (int ct = 0; ct < 8; ++ct)
#pragma unroll
      for (int kc = 0; kc < 4; ++kc) {
        bf16x8 b = *(const bf16x8*)(Blds + ((size_t)((ct << 2) + kc) * 64 + lane) * 8);
        acc[ct] = __builtin_amdgcn_mfma_f32_16x16x32_bf16(a[kc], b, acc[ct], 0, 0, 0);
      }
    const int r0 = (t << 4) + ((lane >> 4) << 2);
    const int cb = lane & 15;
    int sn[4], dn[4];
#pragma unroll
    for (int j = 0; j < 4; ++j) {
      sn[j] = srcp[r0 + j];
      dn[j] = dstp[r0 + j];
    }
#pragma unroll
    for (int ct = 0; ct < 8; ++ct) {
      int c = (ct << 4) + cb;
      float bv = be[c];
      float run = 0.f;
      int prev = dn[0];
#pragma unroll
      for (int j = 0; j < 4; ++j) {
        float xv = bf2f(x[(size_t)sn[j] * H + c]);
        float msg = fmaxf(0.f, xv + acc[ct][j] + bv);
        if (dn[j] != prev) {  // uniform within each 16-lane group
          atomicAdd(h + (size_t)prev * H + c, run);
          run = 0.f;
          prev = dn[j];
        }
        run += msg;
      }
      atomicAdd(h + (size_t)prev * H + c, run);
    }
  }
}

// ---------------- h = x (bf16 -> f32), pairwise ----------------
__global__ void k_hinit(const unsigned short* __restrict__ x, float* __restrict__ h, int NH2) {
  int i = blockIdx.x * blockDim.x + threadIdx.x;
  if (i < NH2) {
    unsigned int pk = ((const unsigned int*)x)[i];
    ((float2*)h)[i] = make_float2(bf2f(pk & 0xffffu), bf2f(pk >> 16));
  }
}

// ---------------- conv1 edge->node: h1[dstp[ei]] += relu(1 + z2p[ei].We1 + be1) ----------------
__global__ void k_msg1(const unsigned short* __restrict__ z2p, const float* __restrict__ We1,
                       const float* __restrict__ be1, const int* __restrict__ dstp,
                       float* __restrict__ h1, int E) {
  const int lane = threadIdx.x & 63;
  const int wid = (blockIdx.x * blockDim.x + threadIdx.x) >> 6;
  const int nw = (gridDim.x * blockDim.x) >> 6;
  const int c0 = lane * 2;
  const float w0 = We1[c0], w1 = We1[c0 + 1];
  const float be = be1[0];
  for (int ei = wid; ei < E; ei += nw) {
    unsigned int pk = *(const unsigned int*)(z2p + (size_t)ei * H + c0);
    float d = bf2f(pk & 0xffffu) * w0 + bf2f(pk >> 16) * w1;
    d = wave_sum(d);
    if (lane == 0) atomicAdd(h1 + dstp[ei], fmaxf(0.f, 1.0f + d + be));
  }
}

// ---------------- conv1 first MLP (rank-1): x[n][c] = relu((1+h1[n])*W1a[c] + b1a[c]) ------
__global__ void k_c1a(const float* __restrict__ h1, const float* __restrict__ W1a,
                      const float* __restrict__ b1a, unsigned short* __restrict__ x, int N) {
  int idx = blockIdx.x * blockDim.x + threadIdx.x;
  int n = idx >> 6;
  if (n >= N) return;
  int c0 = (idx & 63) * 2;
  float hv = 1.0f + h1[n];
  float y0 = fmaxf(0.f, fmaf(hv, W1a[c0], b1a[c0]));
  float y1 = fmaxf(0.f, fmaf(hv, W1a[c0 + 1], b1a[c0 + 1]));
  unsigned int pack = ((unsigned int)f2bf(y1) << 16) | f2bf(y0);
  *(unsigned int*)(x + (size_t)n * H + c0) = pack;
}

// ---------------- pool ----------------
__global__ void k_pool(const unsigned short* __restrict__ x, const int* __restrict__ batch,
                       float* __restrict__ g, int N, int G) {
  __shared__ float red[4][H];
  int gi = blockIdx.x;
  int lane = threadIdx.x & 63;
  int w = threadIdx.x >> 6;
  int lo = lb(batch, N, gi), hi = lb(batch, N, gi + 1);
  float a0 = 0.f, a1 = 0.f;
  for (int n = lo + w; n < hi; n += 4) {
    unsigned int pk = *(const unsigned int*)(x + (size_t)n * H + lane * 2);
    a0 += bf2f(pk & 0xffffu);
    a1 += bf2f(pk >> 16);
  }
  red[w][2 * lane] = a0;
  red[w][2 * lane + 1] = a1;
  __syncthreads();
  if (w == 0) {
    a0 = red[0][2 * lane] + red[1][2 * lane] + red[2][2 * lane] + red[3][2 * lane];
    a1 = red[0][2 * lane + 1] + red[1][2 * lane + 1] + red[2][2 * lane + 1] + red[3][2 * lane + 1];
    *(float2*)(g + (size_t)gi * H + 2 * lane) = make_float2(a0, a1);
  }
}

// ---------------- head ----------------
__global__ void k_head(const float* __restrict__ g, const float* __restrict__ Wl1,
                       const float* __restrict__ bl1, const float* __restrict__ Wl2,
                       const float* __restrict__ bl2, float* __restrict__ out, int G) {
  int gi = blockIdx.x;
  int lane = threadIdx.x & 63;
  const int c0 = 2 * lane, c1 = c0 + 1;
  float2 gv = *(const float2*)(g + (size_t)gi * H + c0);
  float m0 = bl1[c0], m1 = bl1[c1];
#pragma unroll
  for (int k = 0; k < H; ++k) {
    float s = __shfl((k & 1) ? gv.y : gv.x, k >> 1);
    float2 w = *(const float2*)(Wl1 + k * H + c0);
    m0 = fmaf(s, w.x, m0);
    m1 = fmaf(s, w.y, m1);
  }
  float t0 = fmaxf(0.f, m0), t1 = fmaxf(0.f, m1);
  float L0 = bl2[c0], L1 = bl2[c1];
#pragma unroll
  for (int k = 0; k < H; ++k) {
    float s = __shfl((k & 1) ? t1 : t0, k >> 1);
    float2 w = *(const float2*)(Wl2 + k * H + c0);
    L0 = fmaf(s, w.x, L0);
    L1 = fmaf(s, w.y, L1);
  }
  float mx = wave_max(fmaxf(L0, L1));
  float sm = wave_sum(expf(L0 - mx) + expf(L1 - mx));
  float lse = mx + logf(sm);
  *(float2*)(out + (size_t)gi * H + c0) = make_float2(L0 - lse, L1 - lse);
}

__global__ void k_zero_out(float* __restrict__ out, int n) {
  int i = blockIdx.x * blockDim.x + threadIdx.x;
  if (i < n) out[i] = 0.f;
}

extern "C" void kernel_launch(void* const* d_in, const int* in_sizes, int n_in,
                              void* d_out, int out_size, void* d_ws, size_t ws_size,
                              hipStream_t stream) {
  const int* edge_index = (const int*)d_in[0];
  const int* batch = (const int*)d_in[1];
  const int* pos_index = (const int*)d_in[2];
  const float* pos_enc = (const float*)d_in[3];
  const int* pos_batch = (const int*)d_in[4];
  const float* z_table = (const float*)d_in[5];
  const float* bn1_g = (const float*)d_in[6];
  const float* bn1_b = (const float*)d_in[7];
  const float* Wz = (const float*)d_in[8];
  const float* bz = (const float*)d_in[9];
  const float* bn2_g = (const float*)d_in[10];
  const float* bn2_b = (const float*)d_in[11];
  const float* We1 = (const float*)d_in[12];
  const float* be1 = (const float*)d_in[13];
  const float* W1a = (const float*)d_in[14];
  const float* b1a = (const float*)d_in[15];
  const float* W1b = (const float*)d_in[16];
  const float* b1b = (const float*)d_in[17];
  const float* We = (const float*)d_in[18];
  const float* be = (const float*)d_in[19];
  const float* Wa = (const float*)d_in[20];
  const float* ba = (const float*)d_in[21];
  const float* Wb = (const float*)d_in[22];
  const float* bb = (const float*)d_in[23];
  const float* Wl1 = (const float*)d_in[24];
  const float* bl1 = (const float*)d_in[25];
  const float* Wl2 = (const float*)d_in[26];
  const float* bl2 = (const float*)d_in[27];

  const int E = in_sizes[0] / 2;
  const int N = in_sizes[1];
  const int P = in_sizes[2];
  const int L = in_sizes[18] / (H * H);
  const int G = out_size / H;
  const int* src = edge_index;
  const int* dst = edge_index + E;

  char* wsb = (char*)d_ws;
  size_t o = 0;
  auto alloc = [&](size_t bytes) -> void* {
    o = (o + 255) & ~(size_t)255;
    void* p = wsb + o;
    o += bytes;
    return p;
  };
  unsigned short* z2p = (unsigned short*)alloc((size_t)E * H * 2);  // 204.8 MB, CSR-permuted
  unsigned short* x = (unsigned short*)alloc((size_t)N * H * 2);    // 12.8 MB
  float* h = (float*)alloc((size_t)N * H * 4);                      // 25.6 MB
  float* h1 = (float*)alloc((size_t)N * 4);
  int* cnt = (int*)alloc((size_t)N * 4);
  int* off = (int*)alloc((size_t)(N + 1) * 4);
  int* cur = (int*)alloc((size_t)N * 4);
  int* srcp = (int*)alloc((size_t)E * 4);  // holds eids first, then src[eids] in place
  int* dstp = (int*)alloc((size_t)E * 4);
  int* pos_off = (int*)alloc((size_t)(E + 1) * 4);
  float* g = (float*)alloc((size_t)G * H * 4);
  (void)n_in;

  if (o > ws_size) {  // fail fast instead of OOB queue hang
    k_zero_out<<<(out_size + 255) / 256, 256, 0, stream>>>((float*)d_out, out_size);
    return;
  }

  hipMemsetAsync(cnt, 0, (size_t)N * 4, stream);
  hipMemsetAsync(h1, 0, (size_t)N * 4, stream);

  // CSR + permutation metadata
  k_count<<<(E + 255) / 256, 256, 0, stream>>>(dst, cnt, E);
  k_scan<<<1, 1024, 0, stream>>>(cnt, off, cur, N);
  k_scatter<<<(E + 255) / 256, 256, 0, stream>>>(dst, cur, srcp /*eids*/, E);
  k_dstp<<<(N + 255) / 256, 256, 0, stream>>>(off, dstp, N);
  k_posoff<<<(P + 255) / 256, 256, 0, stream>>>(pos_batch, pos_off, P, E);

  // edge embedding
  k_za<<<2048, 256, 0, stream>>>(srcp /*eids*/, pos_off, pos_index, pos_enc, z_table, bn1_g,
                                 bn1_b, z2p, E);
  k_srcp<<<(E + 255) / 256, 256, 0, stream>>>(src, srcp, E);  // eids -> src[eids] in place
  k_gemm<1, 1, 1><<<2048, 256, 0, stream>>>(z2p, z2p, Wz, bz, bn2_g, bn2_b, E);

  // conv1
  k_msg1<<<2048, 256, 0, stream>>>(z2p, We1, be1, dstp, h1, E);
  k_c1a<<<(N * 64 + 255) / 256, 256, 0, stream>>>(h1, W1a, b1a, x, N);
  k_gemm<1, 0, 1><<<782, 256, 0, stream>>>(x, x, W1b, b1b, nullptr, nullptr, N);

  // GINE layers
  const int NH2 = N * H / 2;
  for (int l = 0; l < L; ++l) {
    k_hinit<<<(NH2 + 255) / 256, 256, 0, stream>>>(x, h, NH2);
    k_agg_mfma<<<2048, 256, 0, stream>>>(x, z2p, We + (size_t)l * H * H, be + (size_t)l * H,
                                         srcp, dstp, h, E);
    k_gemm<0, 0, 0><<<782, 256, 0, stream>>>(h, h, Wa + (size_t)l * H * H, ba + (size_t)l * H,
                                             nullptr, nullptr, N);
    k_gemm<0, 0, 1><<<782, 256, 0, stream>>>(h, x, Wb + (size_t)l * H * H, bb + (size_t)l * H,
                                             nullptr, nullptr, N);
  }

  k_pool<<<G, 256, 0, stream>>>(x, batch, g, N, G);
  k_head<<<G, 64, 0, stream>>>(g, Wl1, bl1, Wl2, bl2, (float*)d_out, G);
}

// Round 4
// 2236.217 us; speedup vs baseline: 18.3562x; 1.0661x over previous
//
#include <hip/hip_runtime.h>
#include <hip/hip_bf16.h>

#define H 128

typedef __attribute__((ext_vector_type(8))) short bf16x8;  // 8 bf16 = 4 VGPR
typedef __attribute__((ext_vector_type(4))) float f32x4;

__device__ __forceinline__ float bf2f(unsigned int u16) {
  union { float f; unsigned int i; } v;
  v.i = u16 << 16;
  return v.f;
}
__device__ __forceinline__ unsigned short f2bf(float f) {
  union { float f; unsigned int i; } v;
  v.f = f;
  unsigned int lsb = (v.i >> 16) & 1u;
  v.i += 0x7fffu + lsb;  // RNE
  return (unsigned short)(v.i >> 16);
}

__device__ __forceinline__ int lb(const int* __restrict__ a, int n, int v) {
  int lo = 0, hi = n;
  while (lo < hi) { int m = (lo + hi) >> 1; if (a[m] < v) lo = m + 1; else hi = m; }
  return lo;
}

__device__ __forceinline__ float wave_sum(float v) {
#pragma unroll
  for (int off = 32; off > 0; off >>= 1) v += __shfl_xor(v, off);
  return v;
}
__device__ __forceinline__ float wave_max(float v) {
#pragma unroll
  for (int off = 32; off > 0; off >>= 1) v = fmaxf(v, __shfl_xor(v, off));
  return v;
}

// Stage W (f32 [128][128], row=k, col=c) into LDS as MFMA B-fragments, fragment-linear:
// entry e = (ct*4+kc)*64+lane holds the bf16x8 lane `lane` needs for col-tile ct, k-chunk kc.
// B frag layout (16x16x32): lane holds B[k = kc*32 + 8*(lane>>4) + j][col = ct*16 + (lane&15)].
__device__ __forceinline__ void stage_B(const float* __restrict__ W, short* __restrict__ lds) {
  for (int e = threadIdx.x; e < 8 * 4 * 64; e += blockDim.x) {
    int lane = e & 63;
    int kc = (e >> 6) & 3;
    int ct = e >> 8;
    int col = ct * 16 + (lane & 15);
    int k0 = kc * 32 + (lane >> 4) * 8;
    bf16x8 pack;
#pragma unroll
    for (int j = 0; j < 8; ++j) pack[j] = (short)f2bf(W[(k0 + j) * H + col]);
    *(bf16x8*)(lds + (size_t)e * 8) = pack;
  }
}

// ---------------- CSR build ----------------
__global__ void k_count(const int* __restrict__ dst, int* __restrict__ cnt, int E) {
  int i = blockIdx.x * blockDim.x + threadIdx.x;
  if (i < E) atomicAdd(cnt + dst[i], 1);
}

__global__ void k_scan(const int* __restrict__ cnt, int* __restrict__ off,
                       int* __restrict__ cur, int N) {
  __shared__ int part[1024];
  int t = threadIdx.x;
  int C = (N + 1023) / 1024;
  int beg = t * C, end = min(beg + C, N);
  int s = 0;
  for (int i = beg; i < end; ++i) s += cnt[i];
  part[t] = s;
  __syncthreads();
  for (int d = 1; d < 1024; d <<= 1) {
    int v = (t >= d) ? part[t - d] : 0;
    __syncthreads();
    part[t] += v;
    __syncthreads();
  }
  int run = (t == 0) ? 0 : part[t - 1];
  for (int i = beg; i < end; ++i) {
    off[i] = run; cur[i] = run;
    run += cnt[i];
  }
  if (t == 1023) off[N] = part[1023];
}

__global__ void k_scatter(const int* __restrict__ dst, int* __restrict__ cur,
                          int* __restrict__ eids, int E) {
  int i = blockIdx.x * blockDim.x + threadIdx.x;
  if (i < E) { int p = atomicAdd(cur + dst[i], 1); eids[p] = i; }
}

__global__ void k_dstp(const int* __restrict__ off, int* __restrict__ dstp, int N) {
  int n = blockIdx.x * blockDim.x + threadIdx.x;
  if (n < N) {
    int lo = off[n], hi = off[n + 1];
    for (int i = lo; i < hi; ++i) dstp[i] = n;
  }
}

// in-place: eids[i] -> src[eids[i]]
__global__ void k_srcp(const int* __restrict__ src, int* __restrict__ e2s, int E) {
  int i = blockIdx.x * blockDim.x + threadIdx.x;
  if (i < E) e2s[i] = src[e2s[i]];
}

// pos_off[e] = first p with pos_batch[p] >= e
__global__ void k_posoff(const int* __restrict__ pos_batch, int* __restrict__ pos_off,
                         int P, int E) {
  int p = blockIdx.x * blockDim.x + threadIdx.x;
  if (p >= P) return;
  int b = pos_batch[p];
  int prev = (p == 0) ? -1 : pos_batch[p - 1];
  for (int q = prev + 1; q <= b; ++q) pos_off[q] = p;
  if (p == P - 1)
    for (int q = b + 1; q <= E; ++q) pos_off[q] = P;
}

// ---------------- fused edge embedding ----------------
// Per 16-edge tile: segment-sum gather (z_table L2-resident) -> bn1+relu -> bf16 A-frags
// -> MFMA with Wz -> bn2+relu -> z2p (bf16, CSR order) + msg1 dot(We1) -> atomic h1.
__global__ void k_zfused(const int* __restrict__ eids, const int* __restrict__ pos_off,
                         const int* __restrict__ pos_index, const float* __restrict__ pos_enc,
                         const float* __restrict__ z_table, const float* __restrict__ bn1_g,
                         const float* __restrict__ bn1_b, const float* __restrict__ Wz,
                         const float* __restrict__ bz, const float* __restrict__ bn2_g,
                         const float* __restrict__ bn2_b, const float* __restrict__ We1,
                         const float* __restrict__ be1, const int* __restrict__ dstp,
                         float* __restrict__ h1, unsigned short* __restrict__ z2p, int E) {
  __shared__ short Blds[8 * 4 * 64 * 8];  // 32 KiB
  __shared__ float s_g1[H], s_b1[H], s_g2[H], s_b2[H], s_bz[H], s_w1[H];
  stage_B(Wz, Blds);
  const float inv = rsqrtf(1.0f + 1e-5f);
  for (int i = threadIdx.x; i < H; i += blockDim.x) {
    s_g1[i] = bn1_g[i] * inv;
    s_b1[i] = bn1_b[i];
    s_g2[i] = bn2_g[i] * inv;
    s_b2[i] = bn2_b[i];
    s_bz[i] = bz[i];
    s_w1[i] = We1[i];
  }
  __syncthreads();
  const int lane = threadIdx.x & 63;
  const int wv = threadIdx.x >> 6;
  const int cb = lane & 15;  // A-row within tile / D-col base
  const int g = lane >> 4;
  const int tiles = E >> 4;
  const int nw = (gridDim.x * blockDim.x) >> 6;
  const float be = be1[0];
  for (int t = blockIdx.x * (blockDim.x >> 6) + wv; t < tiles; t += nw) {
    const int ei = (t << 4) + cb;
    int e = eids[ei];
    int lo = pos_off[e], hi = pos_off[e + 1];
    float za[4][8];
#pragma unroll
    for (int kc = 0; kc < 4; ++kc)
#pragma unroll
      for (int j = 0; j < 8; ++j) za[kc][j] = 0.f;
    for (int p = lo; p < hi; ++p) {
      int r = pos_index[p];
      float w = pos_enc[p];
      const float* base = z_table + (size_t)r * H + g * 8;
#pragma unroll
      for (int kc = 0; kc < 4; ++kc) {
        float4 v0 = *(const float4*)(base + kc * 32);
        float4 v1 = *(const float4*)(base + kc * 32 + 4);
        za[kc][0] = fmaf(w, v0.x, za[kc][0]);
        za[kc][1] = fmaf(w, v0.y, za[kc][1]);
        za[kc][2] = fmaf(w, v0.z, za[kc][2]);
        za[kc][3] = fmaf(w, v0.w, za[kc][3]);
        za[kc][4] = fmaf(w, v1.x, za[kc][4]);
        za[kc][5] = fmaf(w, v1.y, za[kc][5]);
        za[kc][6] = fmaf(w, v1.z, za[kc][6]);
        za[kc][7] = fmaf(w, v1.w, za[kc][7]);
      }
    }
    bf16x8 a[4];
#pragma unroll
    for (int kc = 0; kc < 4; ++kc)
#pragma unroll
      for (int j = 0; j < 8; ++j) {
        int c = kc * 32 + g * 8 + j;
        float y = fmaxf(0.f, fmaf(za[kc][j], s_g1[c], s_b1[c]));
        a[kc][j] = (short)f2bf(y);
      }
    f32x4 acc[8];
#pragma unroll
    for (int ct = 0; ct < 8; ++ct) acc[ct] = (f32x4){0.f, 0.f, 0.f, 0.f};
#pragma unroll
    for (int ct = 0; ct < 8; ++ct)
#pragma unroll
      for (int kc = 0; kc < 4; ++kc) {
        bf16x8 b = *(const bf16x8*)(Blds + ((size_t)((ct << 2) + kc) * 64 + lane) * 8);
        acc[ct] = __builtin_amdgcn_mfma_f32_16x16x32_bf16(a[kc], b, acc[ct], 0, 0, 0);
      }
    const int r0 = (t << 4) + (g << 2);
    float msg[4] = {0.f, 0.f, 0.f, 0.f};
#pragma unroll
    for (int ct = 0; ct < 8; ++ct) {
      int c = (ct << 4) + cb;
      float bv = s_bz[c], gv = s_g2[c], b2 = s_b2[c], w1 = s_w1[c];
#pragma unroll
      for (int j = 0; j < 4; ++j) {
        float y = fmaxf(0.f, fmaf(acc[ct][j] + bv, gv, b2));
        z2p[(size_t)(r0 + j) * H + c] = f2bf(y);
        msg[j] = fmaf(y, w1, msg[j]);
      }
    }
#pragma unroll
    for (int j = 0; j < 4; ++j)
#pragma unroll
      for (int o2 = 8; o2 > 0; o2 >>= 1) msg[j] += __shfl_xor(msg[j], o2);
    if (cb == 0) {
#pragma unroll
      for (int j = 0; j < 4; ++j)
        atomicAdd(h1 + dstp[r0 + j], fmaxf(0.f, 1.0f + msg[j] + be));
    }
  }
}

// ---------------- generic MFMA GEMM over 128 cols, K=128: out = epi(in @ W + bias) -------------
// Rows R must be a multiple of 16. In-place safe (tile rows fully in regs before store).
// DUAL: additionally store the f32 result to h_out (h-init for the next agg layer).
template <int IN_BF16, int OUT_BF16, int DUAL>
__global__ void k_gemm(const void* __restrict__ in, void* __restrict__ out,
                       const float* __restrict__ W, const float* __restrict__ bias,
                       float* __restrict__ h_out, int R) {
  __shared__ short Blds[8 * 4 * 64 * 8];  // 32 KiB
  stage_B(W, Blds);
  __syncthreads();
  const int lane = threadIdx.x & 63;
  const int wv = threadIdx.x >> 6;
  const int tiles = R >> 4;
  const int nw = (gridDim.x * blockDim.x) >> 6;
  for (int t = blockIdx.x * (blockDim.x >> 6) + wv; t < tiles; t += nw) {
    const int arow = (t << 4) + (lane & 15);
    bf16x8 a[4];
    if (IN_BF16) {
      const short* ib = (const short*)in;
#pragma unroll
      for (int kc = 0; kc < 4; ++kc)
        a[kc] = *(const bf16x8*)(ib + (size_t)arow * H + kc * 32 + (lane >> 4) * 8);
    } else {
      const float* iff = (const float*)in;
#pragma unroll
      for (int kc = 0; kc < 4; ++kc) {
        const float* p = iff + (size_t)arow * H + kc * 32 + (lane >> 4) * 8;
#pragma unroll
        for (int j = 0; j < 8; ++j) a[kc][j] = (short)f2bf(p[j]);
      }
    }
    f32x4 acc[8];
#pragma unroll
    for (int ct = 0; ct < 8; ++ct) acc[ct] = (f32x4){0.f, 0.f, 0.f, 0.f};
#pragma unroll
    for (int ct = 0; ct < 8; ++ct)
#pragma unroll
      for (int kc = 0; kc < 4; ++kc) {
        bf16x8 b = *(const bf16x8*)(Blds + ((size_t)((ct << 2) + kc) * 64 + lane) * 8);
        acc[ct] = __builtin_amdgcn_mfma_f32_16x16x32_bf16(a[kc], b, acc[ct], 0, 0, 0);
      }
    const int r0 = (t << 4) + ((lane >> 4) << 2);
    const int cb = lane & 15;
#pragma unroll
    for (int ct = 0; ct < 8; ++ct) {
      int c = (ct << 4) + cb;
      float bv = bias[c];
#pragma unroll
      for (int j = 0; j < 4; ++j) {
        float y = fmaxf(acc[ct][j] + bv, 0.f);
        size_t idx = (size_t)(r0 + j) * H + c;
        if (OUT_BF16) ((unsigned short*)out)[idx] = f2bf(y);
        else ((float*)out)[idx] = y;
        if (DUAL) h_out[idx] = y;
      }
    }
  }
}

// ---------------- fused GINE aggregation: h[dst] += relu(x[src] + z2p@We + be) ----------------
__global__ void k_agg_mfma(const unsigned short* __restrict__ x,
                           const unsigned short* __restrict__ z2p,
                           const float* __restrict__ We, const float* __restrict__ be,
                           const int* __restrict__ srcp, const int* __restrict__ dstp,
                           float* __restrict__ h, int E) {
  __shared__ short Blds[8 * 4 * 64 * 8];
  __shared__ float s_be[H];
  stage_B(We, Blds);
  for (int i = threadIdx.x; i < H; i += blockDim.x) s_be[i] = be[i];
  __syncthreads();
  const int lane = threadIdx.x & 63;
  const int wv = threadIdx.x >> 6;
  const int cb = lane & 15;
  const int g = lane >> 4;
  const int tiles = E >> 4;
  const int nw = (gridDim.x * blockDim.x) >> 6;
  for (int t = blockIdx.x * (blockDim.x >> 6) + wv; t < tiles; t += nw) {
    const int arow = (t << 4) + cb;
    bf16x8 a[4];
#pragma unroll
    for (int kc = 0; kc < 4; ++kc)
      a[kc] = *(const bf16x8*)((const short*)z2p + (size_t)arow * H + kc * 32 + g * 8);
    f32x4 acc[8];
#pragma unroll
    for (int ct = 0; ct < 8; ++ct) acc[ct] = (f32x4){0.f, 0.f, 0.f, 0.f};
#pragma unroll
    for (int ct = 0; ct < 8; ++ct)
#pragma unroll
      for (int kc = 0; kc < 4; ++kc) {
        bf16x8 b = *(const bf16x8*)(Blds + ((size_t)((ct << 2) + kc) * 64 + lane) * 8);
        acc[ct] = __builtin_amdgcn_mfma_f32_16x16x32_bf16(a[kc], b, acc[ct], 0, 0, 0);
      }
    const int r0 = (t << 4) + (g << 2);
    int sn[4];
#pragma unroll
    for (int j = 0; j < 4; ++j) sn[j] = srcp[r0 + j];
    const int dlo = dstp[t << 4], dhi = dstp[(t << 4) + 15];
    if (dlo == dhi) {  // whole tile -> one node (wave-uniform)
#pragma unroll
      for (int ct = 0; ct < 8; ++ct) {
        int c = (ct << 4) + cb;
        float bv = s_be[c];
        float run = 0.f;
#pragma unroll
        for (int j = 0; j < 4; ++j) {
          float xv = bf2f(x[(size_t)sn[j] * H + c]);
          run += fmaxf(0.f, xv + acc[ct][j] + bv);
        }
        run += __shfl_xor(run, 16);
        run += __shfl_xor(run, 32);
        if (g == 0) atomicAdd(h + (size_t)dlo * H + c, run);
      }
    } else {
      int dn[4];
#pragma unroll
      for (int j = 0; j < 4; ++j) dn[j] = dstp[r0 + j];
#pragma unroll
      for (int ct = 0; ct < 8; ++ct) {
        int c = (ct << 4) + cb;
        float bv = s_be[c];
        float run = 0.f;
        int prev = dn[0];
#pragma unroll
        for (int j = 0; j < 4; ++j) {
          float xv = bf2f(x[(size_t)sn[j] * H + c]);
          float msg = fmaxf(0.f, xv + acc[ct][j] + bv);
          if (dn[j] != prev) {
            atomicAdd(h + (size_t)prev * H + c, run);
            run = 0.f;
            prev = dn[j];
          }
          run += msg;
        }
        atomicAdd(h + (size_t)prev * H + c, run);
      }
    }
  }
}

// ---------------- conv1 first MLP (rank-1): x[n][c] = relu((1+h1[n])*W1a[c] + b1a[c]) ------
__global__ void k_c1a(const float* __restrict__ h1, const float* __restrict__ W1a,
                      const float* __restrict__ b1a, unsigned short* __restrict__ x, int N) {
  int idx = blockIdx.x * blockDim.x + threadIdx.x;
  int n = idx >> 6;
  if (n >= N) return;
  int c0 = (idx & 63) * 2;
  float hv = 1.0f + h1[n];
  float y0 = fmaxf(0.f, fmaf(hv, W1a[c0], b1a[c0]));
  float y1 = fmaxf(0.f, fmaf(hv, W1a[c0 + 1], b1a[c0 + 1]));
  unsigned int pack = ((unsigned int)f2bf(y1) << 16) | f2bf(y0);
  *(unsigned int*)(x + (size_t)n * H + c0) = pack;
}

// ---------------- pool ----------------
__global__ void k_pool(const unsigned short* __restrict__ x, const int* __restrict__ batch,
                       float* __restrict__ g, int N, int G) {
  __shared__ float red[4][H];
  int gi = blockIdx.x;
  int lane = threadIdx.x & 63;
  int w = threadIdx.x >> 6;
  int lo = lb(batch, N, gi), hi = lb(batch, N, gi + 1);
  float a0 = 0.f, a1 = 0.f;
  for (int n = lo + w; n < hi; n += 4) {
    unsigned int pk = *(const unsigned int*)(x + (size_t)n * H + lane * 2);
    a0 += bf2f(pk & 0xffffu);
    a1 += bf2f(pk >> 16);
  }
  red[w][2 * lane] = a0;
  red[w][2 * lane + 1] = a1;
  __syncthreads();
  if (w == 0) {
    a0 = red[0][2 * lane] + red[1][2 * lane] + red[2][2 * lane] + red[3][2 * lane];
    a1 = red[0][2 * lane + 1] + red[1][2 * lane + 1] + red[2][2 * lane + 1] + red[3][2 * lane + 1];
    *(float2*)(g + (size_t)gi * H + 2 * lane) = make_float2(a0, a1);
  }
}

// ---------------- head ----------------
__global__ void k_head(const float* __restrict__ g, const float* __restrict__ Wl1,
                       const float* __restrict__ bl1, const float* __restrict__ Wl2,
                       const float* __restrict__ bl2, float* __restrict__ out, int G) {
  int gi = blockIdx.x;
  int lane = threadIdx.x & 63;
  const int c0 = 2 * lane, c1 = c0 + 1;
  float2 gv = *(const float2*)(g + (size_t)gi * H + c0);
  float m0 = bl1[c0], m1 = bl1[c1];
#pragma unroll
  for (int k = 0; k < H; ++k) {
    float s = __shfl((k & 1) ? gv.y : gv.x, k >> 1);
    float2 w = *(const float2*)(Wl1 + k * H + c0);
    m0 = fmaf(s, w.x, m0);
    m1 = fmaf(s, w.y, m1);
  }
  float t0 = fmaxf(0.f, m0), t1 = fmaxf(0.f, m1);
  float L0 = bl2[c0], L1 = bl2[c1];
#pragma unroll
  for (int k = 0; k < H; ++k) {
    float s = __shfl((k & 1) ? t1 : t0, k >> 1);
    float2 w = *(const float2*)(Wl2 + k * H + c0);
    L0 = fmaf(s, w.x, L0);
    L1 = fmaf(s, w.y, L1);
  }
  float mx = wave_max(fmaxf(L0, L1));
  float sm = wave_sum(expf(L0 - mx) + expf(L1 - mx));
  float lse = mx + logf(sm);
  *(float2*)(out + (size_t)gi * H + c0) = make_float2(L0 - lse, L1 - lse);
}

__global__ void k_zero_out(float* __restrict__ out, int n) {
  int i = blockIdx.x * blockDim.x + threadIdx.x;
  if (i < n) out[i] = 0.f;
}

extern "C" void kernel_launch(void* const* d_in, const int* in_sizes, int n_in,
                              void* d_out, int out_size, void* d_ws, size_t ws_size,
                              hipStream_t stream) {
  const int* edge_index = (const int*)d_in[0];
  const int* batch = (const int*)d_in[1];
  const int* pos_index = (const int*)d_in[2];
  const float* pos_enc = (const float*)d_in[3];
  const int* pos_batch = (const int*)d_in[4];
  const float* z_table = (const float*)d_in[5];
  const float* bn1_g = (const float*)d_in[6];
  const float* bn1_b = (const float*)d_in[7];
  const float* Wz = (const float*)d_in[8];
  const float* bz = (const float*)d_in[9];
  const float* bn2_g = (const float*)d_in[10];
  const float* bn2_b = (const float*)d_in[11];
  const float* We1 = (const float*)d_in[12];
  const float* be1 = (const float*)d_in[13];
  const float* W1a = (const float*)d_in[14];
  const float* b1a = (const float*)d_in[15];
  const float* W1b = (const float*)d_in[16];
  const float* b1b = (const float*)d_in[17];
  const float* We = (const float*)d_in[18];
  const float* be = (const float*)d_in[19];
  const float* Wa = (const float*)d_in[20];
  const float* ba = (const float*)d_in[21];
  const float* Wb = (const float*)d_in[22];
  const float* bb = (const float*)d_in[23];
  const float* Wl1 = (const float*)d_in[24];
  const float* bl1 = (const float*)d_in[25];
  const float* Wl2 = (const float*)d_in[26];
  const float* bl2 = (const float*)d_in[27];

  const int E = in_sizes[0] / 2;
  const int N = in_sizes[1];
  const int P = in_sizes[2];
  const int L = in_sizes[18] / (H * H);
  const int G = out_size / H;
  const int* src = edge_index;
  const int* dst = edge_index + E;

  char* wsb = (char*)d_ws;
  size_t o = 0;
  auto alloc = [&](size_t bytes) -> void* {
    o = (o + 255) & ~(size_t)255;
    void* p = wsb + o;
    o += bytes;
    return p;
  };
  unsigned short* z2p = (unsigned short*)alloc((size_t)E * H * 2);  // 204.8 MB, CSR-permuted
  unsigned short* x = (unsigned short*)alloc((size_t)N * H * 2);    // 12.8 MB
  float* h = (float*)alloc((size_t)N * H * 4);                      // 25.6 MB
  float* h1 = (float*)alloc((size_t)N * 4);
  int* cnt = (int*)alloc((size_t)N * 4);
  int* off = (int*)alloc((size_t)(N + 1) * 4);
  int* cur = (int*)alloc((size_t)N * 4);
  int* srcp = (int*)alloc((size_t)E * 4);  // holds eids first, then src[eids] in place
  int* dstp = (int*)alloc((size_t)E * 4);
  int* pos_off = (int*)alloc((size_t)(E + 1) * 4);
  float* g = (float*)alloc((size_t)G * H * 4);
  (void)n_in;

  if (o > ws_size) {  // fail fast instead of OOB queue hang
    k_zero_out<<<(out_size + 255) / 256, 256, 0, stream>>>((float*)d_out, out_size);
    return;
  }

  hipMemsetAsync(cnt, 0, (size_t)N * 4, stream);
  hipMemsetAsync(h1, 0, (size_t)N * 4, stream);

  // CSR + permutation metadata
  k_count<<<(E + 255) / 256, 256, 0, stream>>>(dst, cnt, E);
  k_scan<<<1, 1024, 0, stream>>>(cnt, off, cur, N);
  k_scatter<<<(E + 255) / 256, 256, 0, stream>>>(dst, cur, srcp /*eids*/, E);
  k_dstp<<<(N + 255) / 256, 256, 0, stream>>>(off, dstp, N);
  k_posoff<<<(P + 255) / 256, 256, 0, stream>>>(pos_batch, pos_off, P, E);

  // fused edge embedding (za + GEMM(Wz) + msg1)
  k_zfused<<<2048, 256, 0, stream>>>(srcp /*eids*/, pos_off, pos_index, pos_enc, z_table,
                                     bn1_g, bn1_b, Wz, bz, bn2_g, bn2_b, We1, be1, dstp, h1,
                                     z2p, E);
  k_srcp<<<(E + 255) / 256, 256, 0, stream>>>(src, srcp, E);  // eids -> src[eids] in place

  // conv1
  k_c1a<<<(N * 64 + 255) / 256, 256, 0, stream>>>(h1, W1a, b1a, x, N);
  k_gemm<1, 1, 1><<<782, 256, 0, stream>>>(x, x, W1b, b1b, h, N);  // x bf16 + h=x f32

  // GINE layers
  for (int l = 0; l < L; ++l) {
    k_agg_mfma<<<2048, 256, 0, stream>>>(x, z2p, We + (size_t)l * H * H, be + (size_t)l * H,
                                         srcp, dstp, h, E);
    k_gemm<0, 0, 0><<<782, 256, 0, stream>>>(h, h, Wa + (size_t)l * H * H, ba + (size_t)l * H,
                                             nullptr, N);
    if (l < L - 1)
      k_gemm<0, 1, 1><<<782, 256, 0, stream>>>(h, x, Wb + (size_t)l * H * H, bb + (size_t)l * H,
                                               h, N);  // x bf16 + h=x f32 for next layer
    else
      k_gemm<0, 1, 0><<<782, 256, 0, stream>>>(h, x, Wb + (size_t)l * H * H, bb + (size_t)l * H,
                                               nullptr, N);
  }

  k_pool<<<G, 256, 0, stream>>>(x, batch, g, N, G);
  k_head<<<G, 64, 0, stream>>>(g, Wl1, bl1, Wl2, bl2, (float*)d_out, G);
}

// Round 5
// 2212.409 us; speedup vs baseline: 18.5538x; 1.0108x over previous
//
#include <hip/hip_runtime.h>
#include <hip/hip_bf16.h>

#define H 128

typedef __attribute__((ext_vector_type(8))) short bf16x8;  // 8 bf16 = 4 VGPR
typedef __attribute__((ext_vector_type(4))) float f32x4;

__device__ __forceinline__ float bf2f(unsigned int u16) {
  union { float f; unsigned int i; } v;
  v.i = u16 << 16;
  return v.f;
}
__device__ __forceinline__ unsigned short f2bf(float f) {
  union { float f; unsigned int i; } v;
  v.f = f;
  unsigned int lsb = (v.i >> 16) & 1u;
  v.i += 0x7fffu + lsb;  // RNE
  return (unsigned short)(v.i >> 16);
}

__device__ __forceinline__ int lb(const int* __restrict__ a, int n, int v) {
  int lo = 0, hi = n;
  while (lo < hi) { int m = (lo + hi) >> 1; if (a[m] < v) lo = m + 1; else hi = m; }
  return lo;
}

__device__ __forceinline__ float wave_sum(float v) {
#pragma unroll
  for (int off = 32; off > 0; off >>= 1) v += __shfl_xor(v, off);
  return v;
}
__device__ __forceinline__ float wave_max(float v) {
#pragma unroll
  for (int off = 32; off > 0; off >>= 1) v = fmaxf(v, __shfl_xor(v, off));
  return v;
}

// Stage W (f32 [128][128], row=k, col=c) into LDS as MFMA B-fragments, fragment-linear:
// entry e = (ct*4+kc)*64+lane holds the bf16x8 lane `lane` needs for col-tile ct, k-chunk kc.
// B frag layout (16x16x32): lane holds B[k = kc*32 + 8*(lane>>4) + j][col = ct*16 + (lane&15)].
__device__ __forceinline__ void stage_B(const float* __restrict__ W, short* __restrict__ lds) {
  for (int e = threadIdx.x; e < 8 * 4 * 64; e += blockDim.x) {
    int lane = e & 63;
    int kc = (e >> 6) & 3;
    int ct = e >> 8;
    int col = ct * 16 + (lane & 15);
    int k0 = kc * 32 + (lane >> 4) * 8;
    bf16x8 pack;
#pragma unroll
    for (int j = 0; j < 8; ++j) pack[j] = (short)f2bf(W[(k0 + j) * H + col]);
    *(bf16x8*)(lds + (size_t)e * 8) = pack;
  }
}

// ---------------- CSR build ----------------
__global__ void k_count(const int* __restrict__ dst, int* __restrict__ cnt, int E) {
  int i = blockIdx.x * blockDim.x + threadIdx.x;
  if (i < E) atomicAdd(cnt + dst[i], 1);
}

__global__ void k_scan(const int* __restrict__ cnt, int* __restrict__ off,
                       int* __restrict__ cur, int N) {
  __shared__ int part[1024];
  int t = threadIdx.x;
  int C = (N + 1023) / 1024;
  int beg = t * C, end = min(beg + C, N);
  int s = 0;
  for (int i = beg; i < end; ++i) s += cnt[i];
  part[t] = s;
  __syncthreads();
  for (int d = 1; d < 1024; d <<= 1) {
    int v = (t >= d) ? part[t - d] : 0;
    __syncthreads();
    part[t] += v;
    __syncthreads();
  }
  int run = (t == 0) ? 0 : part[t - 1];
  for (int i = beg; i < end; ++i) {
    off[i] = run; cur[i] = run;
    run += cnt[i];
  }
  if (t == 1023) off[N] = part[1023];
}

__global__ void k_scatter(const int* __restrict__ dst, int* __restrict__ cur,
                          int* __restrict__ eids, int E) {
  int i = blockIdx.x * blockDim.x + threadIdx.x;
  if (i < E) { int p = atomicAdd(cur + dst[i], 1); eids[p] = i; }
}

__global__ void k_dstp(const int* __restrict__ off, int* __restrict__ dstp, int N) {
  int n = blockIdx.x * blockDim.x + threadIdx.x;
  if (n < N) {
    int lo = off[n], hi = off[n + 1];
    for (int i = lo; i < hi; ++i) dstp[i] = n;
  }
}

// in-place: eids[i] -> src[eids[i]]
__global__ void k_srcp(const int* __restrict__ src, int* __restrict__ e2s, int E) {
  int i = blockIdx.x * blockDim.x + threadIdx.x;
  if (i < E) e2s[i] = src[e2s[i]];
}

// pos_off[e] = first p with pos_batch[p] >= e
__global__ void k_posoff(const int* __restrict__ pos_batch, int* __restrict__ pos_off,
                         int P, int E) {
  int p = blockIdx.x * blockDim.x + threadIdx.x;
  if (p >= P) return;
  int b = pos_batch[p];
  int prev = (p == 0) ? -1 : pos_batch[p - 1];
  for (int q = prev + 1; q <= b; ++q) pos_off[q] = p;
  if (p == P - 1)
    for (int q = b + 1; q <= E; ++q) pos_off[q] = P;
}

// ---------------- fused edge embedding ----------------
// Per 16-edge tile: for each edge (serial, wave-uniform pos loop) gather the z_table rows
// COALESCED with all 64 lanes (float2/lane), bn1+relu -> bf16 -> LDS tile. Then MFMA with
// Wz from the LDS tile, bn2+relu -> z2p (bf16, CSR order) + fused msg1 dot(We1) -> atomic h1.
#define ZA_STRIDE_U32 68  // 16 rows x 272B (128 bf16 + 8 pad) -> 2-way LDS aliasing only
__global__ __launch_bounds__(256, 2)
void k_zfused(const int* __restrict__ eids, const int* __restrict__ pos_off,
              const int* __restrict__ pos_index, const float* __restrict__ pos_enc,
              const float* __restrict__ z_table, const float* __restrict__ bn1_g,
              const float* __restrict__ bn1_b, const float* __restrict__ Wz,
              const float* __restrict__ bz, const float* __restrict__ bn2_g,
              const float* __restrict__ bn2_b, const float* __restrict__ We1,
              const float* __restrict__ be1, const int* __restrict__ dstp,
              float* __restrict__ h1, unsigned short* __restrict__ z2p, int E) {
  __shared__ short Blds[8 * 4 * 64 * 8];              // 32 KiB
  __shared__ unsigned int za_lds[4][16 * ZA_STRIDE_U32];  // 17 KiB (per-wave tiles)
  __shared__ float s_g1[H], s_b1[H], s_g2[H], s_b2[H], s_bz[H], s_w1[H];
  stage_B(Wz, Blds);
  const float inv = rsqrtf(1.0f + 1e-5f);
  for (int i = threadIdx.x; i < H; i += blockDim.x) {
    s_g1[i] = bn1_g[i] * inv;
    s_b1[i] = bn1_b[i];
    s_g2[i] = bn2_g[i] * inv;
    s_b2[i] = bn2_b[i];
    s_bz[i] = bz[i];
    s_w1[i] = We1[i];
  }
  __syncthreads();
  const int lane = threadIdx.x & 63;
  const int wv = threadIdx.x >> 6;
  const int cb = lane & 15;
  const int g = lane >> 4;
  const int tiles = E >> 4;
  const int nw = (gridDim.x * blockDim.x) >> 6;
  const float be = be1[0];
  unsigned int* zt = za_lds[wv];
  const int c0 = lane * 2;
  const float g1a = s_g1[c0], g1b = s_g1[c0 + 1];
  const float b1a = s_b1[c0], b1b = s_b1[c0 + 1];
  for (int t = blockIdx.x * (blockDim.x >> 6) + wv; t < tiles; t += nw) {
    // ---- gather phase: one edge at a time, wave-uniform, coalesced row reads ----
#pragma unroll 1
    for (int sub = 0; sub < 16; ++sub) {
      int e = eids[(t << 4) + sub];
      int lo = pos_off[e], hi = pos_off[e + 1];
      float a0 = 0.f, a1 = 0.f;
      for (int p = lo; p < hi; ++p) {
        int r = pos_index[p];
        float w = pos_enc[p];
        float2 zr = *(const float2*)(z_table + (size_t)r * H + c0);
        a0 = fmaf(w, zr.x, a0);
        a1 = fmaf(w, zr.y, a1);
      }
      float y0 = fmaxf(0.f, fmaf(a0, g1a, b1a));
      float y1 = fmaxf(0.f, fmaf(a1, g1b, b1b));
      zt[sub * ZA_STRIDE_U32 + lane] = ((unsigned int)f2bf(y1) << 16) | f2bf(y0);
    }
    // ---- A-fragments from LDS (row = edge cb, cols kc*32 + g*8 ..+8) ----
    bf16x8 a[4];
#pragma unroll
    for (int kc = 0; kc < 4; ++kc)
      a[kc] = *(const bf16x8*)((const short*)(zt + cb * ZA_STRIDE_U32) + kc * 32 + g * 8);
    f32x4 acc[8];
#pragma unroll
    for (int ct = 0; ct < 8; ++ct) acc[ct] = (f32x4){0.f, 0.f, 0.f, 0.f};
#pragma unroll
    for (int ct = 0; ct < 8; ++ct)
#pragma unroll
      for (int kc = 0; kc < 4; ++kc) {
        bf16x8 b = *(const bf16x8*)(Blds + ((size_t)((ct << 2) + kc) * 64 + lane) * 8);
        acc[ct] = __builtin_amdgcn_mfma_f32_16x16x32_bf16(a[kc], b, acc[ct], 0, 0, 0);
      }
    const int r0 = (t << 4) + (g << 2);
    float msg[4] = {0.f, 0.f, 0.f, 0.f};
#pragma unroll
    for (int ct = 0; ct < 8; ++ct) {
      int c = (ct << 4) + cb;
      float bv = s_bz[c], gv = s_g2[c], b2 = s_b2[c], w1 = s_w1[c];
#pragma unroll
      for (int j = 0; j < 4; ++j) {
        float y = fmaxf(0.f, fmaf(acc[ct][j] + bv, gv, b2));
        z2p[(size_t)(r0 + j) * H + c] = f2bf(y);
        msg[j] = fmaf(y, w1, msg[j]);
      }
    }
#pragma unroll
    for (int j = 0; j < 4; ++j)
#pragma unroll
      for (int o2 = 8; o2 > 0; o2 >>= 1) msg[j] += __shfl_xor(msg[j], o2);
    if (cb == 0) {
#pragma unroll
      for (int j = 0; j < 4; ++j)
        atomicAdd(h1 + dstp[r0 + j], fmaxf(0.f, 1.0f + msg[j] + be));
    }
  }
}

// ---------------- generic MFMA GEMM over 128 cols, K=128: out = epi(in @ W + bias) -------------
// Rows R must be a multiple of 16. In-place safe (tile rows fully in regs before store).
// DUAL: additionally store the f32 result to h_out (h-init for the next agg layer).
template <int IN_BF16, int OUT_BF16, int DUAL>
__global__ __launch_bounds__(256, 2)
void k_gemm(const void* __restrict__ in, void* __restrict__ out,
            const float* __restrict__ W, const float* __restrict__ bias,
            float* __restrict__ h_out, int R) {
  __shared__ short Blds[8 * 4 * 64 * 8];  // 32 KiB
  stage_B(W, Blds);
  __syncthreads();
  const int lane = threadIdx.x & 63;
  const int wv = threadIdx.x >> 6;
  const int tiles = R >> 4;
  const int nw = (gridDim.x * blockDim.x) >> 6;
  for (int t = blockIdx.x * (blockDim.x >> 6) + wv; t < tiles; t += nw) {
    const int arow = (t << 4) + (lane & 15);
    bf16x8 a[4];
    if (IN_BF16) {
      const short* ib = (const short*)in;
#pragma unroll
      for (int kc = 0; kc < 4; ++kc)
        a[kc] = *(const bf16x8*)(ib + (size_t)arow * H + kc * 32 + (lane >> 4) * 8);
    } else {
      const float* iff = (const float*)in;
#pragma unroll
      for (int kc = 0; kc < 4; ++kc) {
        const float* p = iff + (size_t)arow * H + kc * 32 + (lane >> 4) * 8;
#pragma unroll
        for (int j = 0; j < 8; ++j) a[kc][j] = (short)f2bf(p[j]);
      }
    }
    f32x4 acc[8];
#pragma unroll
    for (int ct = 0; ct < 8; ++ct) acc[ct] = (f32x4){0.f, 0.f, 0.f, 0.f};
#pragma unroll
    for (int ct = 0; ct < 8; ++ct)
#pragma unroll
      for (int kc = 0; kc < 4; ++kc) {
        bf16x8 b = *(const bf16x8*)(Blds + ((size_t)((ct << 2) + kc) * 64 + lane) * 8);
        acc[ct] = __builtin_amdgcn_mfma_f32_16x16x32_bf16(a[kc], b, acc[ct], 0, 0, 0);
      }
    const int r0 = (t << 4) + ((lane >> 4) << 2);
    const int cb = lane & 15;
#pragma unroll
    for (int ct = 0; ct < 8; ++ct) {
      int c = (ct << 4) + cb;
      float bv = bias[c];
#pragma unroll
      for (int j = 0; j < 4; ++j) {
        float y = fmaxf(acc[ct][j] + bv, 0.f);
        size_t idx = (size_t)(r0 + j) * H + c;
        if (OUT_BF16) ((unsigned short*)out)[idx] = f2bf(y);
        else ((float*)out)[idx] = y;
        if (DUAL) h_out[idx] = y;
      }
    }
  }
}

// ---------------- fused GINE aggregation: h[dst] += relu(x[src] + z2p@We + be) ----------------
__global__ __launch_bounds__(256, 2)
void k_agg_mfma(const unsigned short* __restrict__ x,
                const unsigned short* __restrict__ z2p,
                const float* __restrict__ We, const float* __restrict__ be,
                const int* __restrict__ srcp, const int* __restrict__ dstp,
                float* __restrict__ h, int E) {
  __shared__ short Blds[8 * 4 * 64 * 8];
  __shared__ float s_be[H];
  stage_B(We, Blds);
  for (int i = threadIdx.x; i < H; i += blockDim.x) s_be[i] = be[i];
  __syncthreads();
  const int lane = threadIdx.x & 63;
  const int wv = threadIdx.x >> 6;
  const int cb = lane & 15;
  const int g = lane >> 4;
  const int tiles = E >> 4;
  const int nw = (gridDim.x * blockDim.x) >> 6;
  for (int t = blockIdx.x * (blockDim.x >> 6) + wv; t < tiles; t += nw) {
    const int arow = (t << 4) + cb;
    bf16x8 a[4];
#pragma unroll
    for (int kc = 0; kc < 4; ++kc)
      a[kc] = *(const bf16x8*)((const short*)z2p + (size_t)arow * H + kc * 32 + g * 8);
    f32x4 acc[8];
#pragma unroll
    for (int ct = 0; ct < 8; ++ct) acc[ct] = (f32x4){0.f, 0.f, 0.f, 0.f};
#pragma unroll
    for (int ct = 0; ct < 8; ++ct)
#pragma unroll
      for (int kc = 0; kc < 4; ++kc) {
        bf16x8 b = *(const bf16x8*)(Blds + ((size_t)((ct << 2) + kc) * 64 + lane) * 8);
        acc[ct] = __builtin_amdgcn_mfma_f32_16x16x32_bf16(a[kc], b, acc[ct], 0, 0, 0);
      }
    const int r0 = (t << 4) + (g << 2);
    int sn[4];
#pragma unroll
    for (int j = 0; j < 4; ++j) sn[j] = srcp[r0 + j];
    const int dlo = dstp[t << 4], dhi = dstp[(t << 4) + 15];
    if (dlo == dhi) {  // whole tile -> one node (wave-uniform)
#pragma unroll
      for (int ct = 0; ct < 8; ++ct) {
        int c = (ct << 4) + cb;
        float bv = s_be[c];
        float run = 0.f;
#pragma unroll
        for (int j = 0; j < 4; ++j) {
          float xv = bf2f(x[(size_t)sn[j] * H + c]);
          run += fmaxf(0.f, xv + acc[ct][j] + bv);
        }
        run += __shfl_xor(run, 16);
        run += __shfl_xor(run, 32);
        if (g == 0) atomicAdd(h + (size_t)dlo * H + c, run);
      }
    } else {
      int dn[4];
#pragma unroll
      for (int j = 0; j < 4; ++j) dn[j] = dstp[r0 + j];
#pragma unroll
      for (int ct = 0; ct < 8; ++ct) {
        int c = (ct << 4) + cb;
        float bv = s_be[c];
        float run = 0.f;
        int prev = dn[0];
#pragma unroll
        for (int j = 0; j < 4; ++j) {
          float xv = bf2f(x[(size_t)sn[j] * H + c]);
          float msg = fmaxf(0.f, xv + acc[ct][j] + bv);
          if (dn[j] != prev) {
            atomicAdd(h + (size_t)prev * H + c, run);
            run = 0.f;
            prev = dn[j];
          }
          run += msg;
        }
        atomicAdd(h + (size_t)prev * H + c, run);
      }
    }
  }
}

// ---------------- conv1 first MLP (rank-1): x[n][c] = relu((1+h1[n])*W1a[c] + b1a[c]) ------
__global__ void k_c1a(const float* __restrict__ h1, const float* __restrict__ W1a,
                      const float* __restrict__ b1a, unsigned short* __restrict__ x, int N) {
  int idx = blockIdx.x * blockDim.x + threadIdx.x;
  int n = idx >> 6;
  if (n >= N) return;
  int c0 = (idx & 63) * 2;
  float hv = 1.0f + h1[n];
  float y0 = fmaxf(0.f, fmaf(hv, W1a[c0], b1a[c0]));
  float y1 = fmaxf(0.f, fmaf(hv, W1a[c0 + 1], b1a[c0 + 1]));
  unsigned int pack = ((unsigned int)f2bf(y1) << 16) | f2bf(y0);
  *(unsigned int*)(x + (size_t)n * H + c0) = pack;
}

// ---------------- pool ----------------
__global__ void k_pool(const unsigned short* __restrict__ x, const int* __restrict__ batch,
                       float* __restrict__ g, int N, int G) {
  __shared__ float red[4][H];
  int gi = blockIdx.x;
  int lane = threadIdx.x & 63;
  int w = threadIdx.x >> 6;
  int lo = lb(batch, N, gi), hi = lb(batch, N, gi + 1);
  float a0 = 0.f, a1 = 0.f;
  for (int n = lo + w; n < hi; n += 4) {
    unsigned int pk = *(const unsigned int*)(x + (size_t)n * H + lane * 2);
    a0 += bf2f(pk & 0xffffu);
    a1 += bf2f(pk >> 16);
  }
  red[w][2 * lane] = a0;
  red[w][2 * lane + 1] = a1;
  __syncthreads();
  if (w == 0) {
    a0 = red[0][2 * lane] + red[1][2 * lane] + red[2][2 * lane] + red[3][2 * lane];
    a1 = red[0][2 * lane + 1] + red[1][2 * lane + 1] + red[2][2 * lane + 1] + red[3][2 * lane + 1];
    *(float2*)(g + (size_t)gi * H + 2 * lane) = make_float2(a0, a1);
  }
}

// ---------------- head ----------------
__global__ void k_head(const float* __restrict__ g, const float* __restrict__ Wl1,
                       const float* __restrict__ bl1, const float* __restrict__ Wl2,
                       const float* __restrict__ bl2, float* __restrict__ out, int G) {
  int gi = blockIdx.x;
  int lane = threadIdx.x & 63;
  const int c0 = 2 * lane, c1 = c0 + 1;
  float2 gv = *(const float2*)(g + (size_t)gi * H + c0);
  float m0 = bl1[c0], m1 = bl1[c1];
#pragma unroll
  for (int k = 0; k < H; ++k) {
    float s = __shfl((k & 1) ? gv.y : gv.x, k >> 1);
    float2 w = *(const float2*)(Wl1 + k * H + c0);
    m0 = fmaf(s, w.x, m0);
    m1 = fmaf(s, w.y, m1);
  }
  float t0 = fmaxf(0.f, m0), t1 = fmaxf(0.f, m1);
  float L0 = bl2[c0], L1 = bl2[c1];
#pragma unroll
  for (int k = 0; k < H; ++k) {
    float s = __shfl((k & 1) ? t1 : t0, k >> 1);
    float2 w = *(const float2*)(Wl2 + k * H + c0);
    L0 = fmaf(s, w.x, L0);
    L1 = fmaf(s, w.y, L1);
  }
  float mx = wave_max(fmaxf(L0, L1));
  float sm = wave_sum(expf(L0 - mx) + expf(L1 - mx));
  float lse = mx + logf(sm);
  *(float2*)(out + (size_t)gi * H + c0) = make_float2(L0 - lse, L1 - lse);
}

__global__ void k_zero_out(float* __restrict__ out, int n) {
  int i = blockIdx.x * blockDim.x + threadIdx.x;
  if (i < n) out[i] = 0.f;
}

extern "C" void kernel_launch(void* const* d_in, const int* in_sizes, int n_in,
                              void* d_out, int out_size, void* d_ws, size_t ws_size,
                              hipStream_t stream) {
  const int* edge_index = (const int*)d_in[0];
  const int* batch = (const int*)d_in[1];
  const int* pos_index = (const int*)d_in[2];
  const float* pos_enc = (const float*)d_in[3];
  const int* pos_batch = (const int*)d_in[4];
  const float* z_table = (const float*)d_in[5];
  const float* bn1_g = (const float*)d_in[6];
  const float* bn1_b = (const float*)d_in[7];
  const float* Wz = (const float*)d_in[8];
  const float* bz = (const float*)d_in[9];
  const float* bn2_g = (const float*)d_in[10];
  const float* bn2_b = (const float*)d_in[11];
  const float* We1 = (const float*)d_in[12];
  const float* be1 = (const float*)d_in[13];
  const float* W1a = (const float*)d_in[14];
  const float* b1a = (const float*)d_in[15];
  const float* W1b = (const float*)d_in[16];
  const float* b1b = (const float*)d_in[17];
  const float* We = (const float*)d_in[18];
  const float* be = (const float*)d_in[19];
  const float* Wa = (const float*)d_in[20];
  const float* ba = (const float*)d_in[21];
  const float* Wb = (const float*)d_in[22];
  const float* bb = (const float*)d_in[23];
  const float* Wl1 = (const float*)d_in[24];
  const float* bl1 = (const float*)d_in[25];
  const float* Wl2 = (const float*)d_in[26];
  const float* bl2 = (const float*)d_in[27];

  const int E = in_sizes[0] / 2;
  const int N = in_sizes[1];
  const int P = in_sizes[2];
  const int L = in_sizes[18] / (H * H);
  const int G = out_size / H;
  const int* src = edge_index;
  const int* dst = edge_index + E;

  char* wsb = (char*)d_ws;
  size_t o = 0;
  auto alloc = [&](size_t bytes) -> void* {
    o = (o + 255) & ~(size_t)255;
    void* p = wsb + o;
    o += bytes;
    return p;
  };
  unsigned short* z2p = (unsigned short*)alloc((size_t)E * H * 2);  // 204.8 MB, CSR-permuted
  unsigned short* x = (unsigned short*)alloc((size_t)N * H * 2);    // 12.8 MB
  float* h = (float*)alloc((size_t)N * H * 4);                      // 25.6 MB
  float* h1 = (float*)alloc((size_t)N * 4);
  int* cnt = (int*)alloc((size_t)N * 4);
  int* off = (int*)alloc((size_t)(N + 1) * 4);
  int* cur = (int*)alloc((size_t)N * 4);
  int* srcp = (int*)alloc((size_t)E * 4);  // holds eids first, then src[eids] in place
  int* dstp = (int*)alloc((size_t)E * 4);
  int* pos_off = (int*)alloc((size_t)(E + 1) * 4);
  float* g = (float*)alloc((size_t)G * H * 4);
  (void)n_in;

  if (o > ws_size) {  // fail fast instead of OOB queue hang
    k_zero_out<<<(out_size + 255) / 256, 256, 0, stream>>>((float*)d_out, out_size);
    return;
  }

  hipMemsetAsync(cnt, 0, (size_t)N * 4, stream);
  hipMemsetAsync(h1, 0, (size_t)N * 4, stream);

  // CSR + permutation metadata
  k_count<<<(E + 255) / 256, 256, 0, stream>>>(dst, cnt, E);
  k_scan<<<1, 1024, 0, stream>>>(cnt, off, cur, N);
  k_scatter<<<(E + 255) / 256, 256, 0, stream>>>(dst, cur, srcp /*eids*/, E);
  k_dstp<<<(N + 255) / 256, 256, 0, stream>>>(off, dstp, N);
  k_posoff<<<(P + 255) / 256, 256, 0, stream>>>(pos_batch, pos_off, P, E);

  // fused edge embedding (za + GEMM(Wz) + msg1)
  k_zfused<<<2048, 256, 0, stream>>>(srcp /*eids*/, pos_off, pos_index, pos_enc, z_table,
                                     bn1_g, bn1_b, Wz, bz, bn2_g, bn2_b, We1, be1, dstp, h1,
                                     z2p, E);
  k_srcp<<<(E + 255) / 256, 256, 0, stream>>>(src, srcp, E);  // eids -> src[eids] in place

  // conv1
  k_c1a<<<(N * 64 + 255) / 256, 256, 0, stream>>>(h1, W1a, b1a, x, N);
  k_gemm<1, 1, 1><<<782, 256, 0, stream>>>(x, x, W1b, b1b, h, N);  // x bf16 + h=x f32

  // GINE layers
  for (int l = 0; l < L; ++l) {
    k_agg_mfma<<<2048, 256, 0, stream>>>(x, z2p, We + (size_t)l * H * H, be + (size_t)l * H,
                                         srcp, dstp, h, E);
    k_gemm<0, 0, 0><<<782, 256, 0, stream>>>(h, h, Wa + (size_t)l * H * H, ba + (size_t)l * H,
                                             nullptr, N);
    if (l < L - 1)
      k_gemm<0, 1, 1><<<782, 256, 0, stream>>>(h, x, Wb + (size_t)l * H * H, bb + (size_t)l * H,
                                               h, N);  // x bf16 + h=x f32 for next layer
    else
      k_gemm<0, 1, 0><<<782, 256, 0, stream>>>(h, x, Wb + (size_t)l * H * H, bb + (size_t)l * H,
                                               nullptr, N);
  }

  k_pool<<<G, 256, 0, stream>>>(x, batch, g, N, G);
  k_head<<<G, 64, 0, stream>>>(g, Wl1, bl1, Wl2, bl2, (float*)d_out, G);
}

// Round 6
// 1885.511 us; speedup vs baseline: 21.7705x; 1.1734x over previous
//
#include <hip/hip_runtime.h>
#include <hip/hip_bf16.h>

#define H 128

typedef __attribute__((ext_vector_type(8))) short bf16x8;  // 8 bf16 = 4 VGPR
typedef __attribute__((ext_vector_type(4))) float f32x4;

__device__ __forceinline__ float bf2f(unsigned int u16) {
  union { float f; unsigned int i; } v;
  v.i = u16 << 16;
  return v.f;
}
__device__ __forceinline__ unsigned short f2bf(float f) {
  union { float f; unsigned int i; } v;
  v.f = f;
  unsigned int lsb = (v.i >> 16) & 1u;
  v.i += 0x7fffu + lsb;  // RNE
  return (unsigned short)(v.i >> 16);
}

__device__ __forceinline__ int lb(const int* __restrict__ a, int n, int v) {
  int lo = 0, hi = n;
  while (lo < hi) { int m = (lo + hi) >> 1; if (a[m] < v) lo = m + 1; else hi = m; }
  return lo;
}

__device__ __forceinline__ float wave_sum(float v) {
#pragma unroll
  for (int off = 32; off > 0; off >>= 1) v += __shfl_xor(v, off);
  return v;
}
__device__ __forceinline__ float wave_max(float v) {
#pragma unroll
  for (int off = 32; off > 0; off >>= 1) v = fmaxf(v, __shfl_xor(v, off));
  return v;
}

// Stage W (f32 [128][128], row=k, col=c) into LDS as MFMA B-fragments, fragment-linear:
// B frag layout (16x16x32): lane holds B[k = kc*32 + 8*(lane>>4) + j][col = ct*16 + (lane&15)].
__device__ __forceinline__ void stage_B(const float* __restrict__ W, short* __restrict__ lds) {
  for (int e = threadIdx.x; e < 8 * 4 * 64; e += blockDim.x) {
    int lane = e & 63;
    int kc = (e >> 6) & 3;
    int ct = e >> 8;
    int col = ct * 16 + (lane & 15);
    int k0 = kc * 32 + (lane >> 4) * 8;
    bf16x8 pack;
#pragma unroll
    for (int j = 0; j < 8; ++j) pack[j] = (short)f2bf(W[(k0 + j) * H + col]);
    *(bf16x8*)(lds + (size_t)e * 8) = pack;
  }
}

// ---------------- CSR build ----------------
__global__ void k_count(const int* __restrict__ dst, int* __restrict__ cnt, int E) {
  int i = blockIdx.x * blockDim.x + threadIdx.x;
  if (i < E) atomicAdd(cnt + dst[i], 1);
}

__global__ void k_scan(const int* __restrict__ cnt, int* __restrict__ off,
                       int* __restrict__ cur, int N) {
  __shared__ int part[1024];
  int t = threadIdx.x;
  int C = (N + 1023) / 1024;
  int beg = t * C, end = min(beg + C, N);
  int s = 0;
  for (int i = beg; i < end; ++i) s += cnt[i];
  part[t] = s;
  __syncthreads();
  for (int d = 1; d < 1024; d <<= 1) {
    int v = (t >= d) ? part[t - d] : 0;
    __syncthreads();
    part[t] += v;
    __syncthreads();
  }
  int run = (t == 0) ? 0 : part[t - 1];
  for (int i = beg; i < end; ++i) {
    off[i] = run; cur[i] = run;
    run += cnt[i];
  }
  if (t == 1023) off[N] = part[1023];
}

__global__ void k_scatter(const int* __restrict__ dst, int* __restrict__ cur,
                          int* __restrict__ eids, int E) {
  int i = blockIdx.x * blockDim.x + threadIdx.x;
  if (i < E) { int p = atomicAdd(cur + dst[i], 1); eids[p] = i; }
}

__global__ void k_dstp(const int* __restrict__ off, int* __restrict__ dstp, int N) {
  int n = blockIdx.x * blockDim.x + threadIdx.x;
  if (n < N) {
    int lo = off[n], hi = off[n + 1];
    for (int i = lo; i < hi; ++i) dstp[i] = n;
  }
}

// in-place: eids[i] -> src[eids[i]]
__global__ void k_srcp(const int* __restrict__ src, int* __restrict__ e2s, int E) {
  int i = blockIdx.x * blockDim.x + threadIdx.x;
  if (i < E) e2s[i] = src[e2s[i]];
}

// pos_off[e] = first p with pos_batch[p] >= e
__global__ void k_posoff(const int* __restrict__ pos_batch, int* __restrict__ pos_off,
                         int P, int E) {
  int p = blockIdx.x * blockDim.x + threadIdx.x;
  if (p >= P) return;
  int b = pos_batch[p];
  int prev = (p == 0) ? -1 : pos_batch[p - 1];
  for (int q = prev + 1; q <= b; ++q) pos_off[q] = p;
  if (p == P - 1)
    for (int q = b + 1; q <= E; ++q) pos_off[q] = P;
}

// XCD-chunked contiguous work split: wave gw (XCD-contiguous order) gets tiles [t0,t1).
// gridDim.x must be a multiple of 8.
__device__ __forceinline__ void tile_range(int tiles, int wv, int& t0, int& t1) {
  const int W = (gridDim.x * blockDim.x) >> 6;
  const int bswz = ((blockIdx.x & 7) * (gridDim.x >> 3)) + (blockIdx.x >> 3);
  const int gw = bswz * (blockDim.x >> 6) + wv;
  t0 = (int)(((long long)tiles * gw) / W);
  t1 = (int)(((long long)tiles * (gw + 1)) / W);
}

// ---------------- fused edge embedding ----------------
// Per 16-edge tile: per edge, 4 lane-groups split pos entries; 16 lanes read the 512B
// z_table row (32B/lane); shfl-reduce across groups; bn1+relu -> bf16 -> LDS tile.
// Then MFMA with Wz, bn2+relu -> z2p (bf16, CSR order) + fused msg1 dot(We1) -> atomic h1.
#define ZA_STRIDE_S16 136  // 16 rows x 272B (128 bf16 + 8 pad)
__global__ __launch_bounds__(256, 2)
void k_zfused(const int* __restrict__ eids, const int* __restrict__ pos_off,
              const int* __restrict__ pos_index, const float* __restrict__ pos_enc,
              const float* __restrict__ z_table, const float* __restrict__ bn1_g,
              const float* __restrict__ bn1_b, const float* __restrict__ Wz,
              const float* __restrict__ bz, const float* __restrict__ bn2_g,
              const float* __restrict__ bn2_b, const float* __restrict__ We1,
              const float* __restrict__ be1, const int* __restrict__ dstp,
              float* __restrict__ h1, unsigned short* __restrict__ z2p, int E) {
  __shared__ short Blds[8 * 4 * 64 * 8];                 // 32 KiB
  __shared__ short za_lds[4][16 * ZA_STRIDE_S16];        // 17 KiB (per-wave tiles)
  __shared__ float s_g2[H], s_b2[H], s_bz[H], s_w1[H];
  stage_B(Wz, Blds);
  const float inv = rsqrtf(1.0f + 1e-5f);
  for (int i = threadIdx.x; i < H; i += blockDim.x) {
    s_g2[i] = bn2_g[i] * inv;
    s_b2[i] = bn2_b[i];
    s_bz[i] = bz[i];
    s_w1[i] = We1[i];
  }
  __syncthreads();
  const int lane = threadIdx.x & 63;
  const int wv = threadIdx.x >> 6;
  const int cb = lane & 15;  // 16-lane-group index / A-row / D-col base
  const int g = lane >> 4;   // group
  const int tiles = E >> 4;
  const float be = be1[0];
  short* zt = za_lds[wv];
  // per-lane bn1 params for cols cb*8 .. cb*8+7
  float g1r[8], b1r[8];
#pragma unroll
  for (int j = 0; j < 8; ++j) {
    g1r[j] = bn1_g[cb * 8 + j] * inv;
    b1r[j] = bn1_b[cb * 8 + j];
  }
  int t0, t1;
  tile_range(tiles, wv, t0, t1);
  for (int t = t0; t < t1; ++t) {
    // ---- gather phase: groups split pos entries, 16 lanes cover the 128 cols ----
#pragma unroll 1
    for (int sub = 0; sub < 16; ++sub) {
      int e = eids[(t << 4) + sub];
      int lo = pos_off[e], hi = pos_off[e + 1];
      float a[8];
#pragma unroll
      for (int j = 0; j < 8; ++j) a[j] = 0.f;
      for (int p = lo + g; p < hi; p += 4) {
        int r = pos_index[p];
        float w = pos_enc[p];
        const float* row = z_table + (size_t)r * H + cb * 8;
        float4 v0 = *(const float4*)row;
        float4 v1 = *(const float4*)(row + 4);
        a[0] = fmaf(w, v0.x, a[0]);
        a[1] = fmaf(w, v0.y, a[1]);
        a[2] = fmaf(w, v0.z, a[2]);
        a[3] = fmaf(w, v0.w, a[3]);
        a[4] = fmaf(w, v1.x, a[4]);
        a[5] = fmaf(w, v1.y, a[5]);
        a[6] = fmaf(w, v1.z, a[6]);
        a[7] = fmaf(w, v1.w, a[7]);
      }
#pragma unroll
      for (int j = 0; j < 8; ++j) {
        a[j] += __shfl_xor(a[j], 16);
        a[j] += __shfl_xor(a[j], 32);
      }
      if (g == 0) {
        bf16x8 pack;
#pragma unroll
        for (int j = 0; j < 8; ++j)
          pack[j] = (short)f2bf(fmaxf(0.f, fmaf(a[j], g1r[j], b1r[j])));
        *(bf16x8*)(zt + sub * ZA_STRIDE_S16 + cb * 8) = pack;
      }
    }
    __builtin_amdgcn_s_waitcnt(0);  // drain lds writes (wave-private tile)
    // ---- A-fragments from LDS (row = edge cb, cols kc*32 + g*8 ..+8) ----
    bf16x8 a[4];
#pragma unroll
    for (int kc = 0; kc < 4; ++kc)
      a[kc] = *(const bf16x8*)(zt + cb * ZA_STRIDE_S16 + kc * 32 + g * 8);
    f32x4 acc[8];
#pragma unroll
    for (int ct = 0; ct < 8; ++ct) acc[ct] = (f32x4){0.f, 0.f, 0.f, 0.f};
#pragma unroll
    for (int ct = 0; ct < 8; ++ct)
#pragma unroll
      for (int kc = 0; kc < 4; ++kc) {
        bf16x8 b = *(const bf16x8*)(Blds + ((size_t)((ct << 2) + kc) * 64 + lane) * 8);
        acc[ct] = __builtin_amdgcn_mfma_f32_16x16x32_bf16(a[kc], b, acc[ct], 0, 0, 0);
      }
    const int r0 = (t << 4) + (g << 2);
    float msg[4] = {0.f, 0.f, 0.f, 0.f};
#pragma unroll
    for (int ct = 0; ct < 8; ++ct) {
      int c = (ct << 4) + cb;
      float bv = s_bz[c], gv = s_g2[c], b2 = s_b2[c], w1 = s_w1[c];
#pragma unroll
      for (int j = 0; j < 4; ++j) {
        float y = fmaxf(0.f, fmaf(acc[ct][j] + bv, gv, b2));
        z2p[(size_t)(r0 + j) * H + c] = f2bf(y);
        msg[j] = fmaf(y, w1, msg[j]);
      }
    }
#pragma unroll
    for (int j = 0; j < 4; ++j)
#pragma unroll
      for (int o2 = 8; o2 > 0; o2 >>= 1) msg[j] += __shfl_xor(msg[j], o2);
    if (cb == 0) {
#pragma unroll
      for (int j = 0; j < 4; ++j)
        atomicAdd(h1 + dstp[r0 + j], fmaxf(0.f, 1.0f + msg[j] + be));
    }
  }
}

// ---------------- generic MFMA GEMM over 128 cols, K=128: out = epi(in @ W + bias) -------------
// Rows R must be a multiple of 16. In-place safe (tile rows fully in regs before store).
// DUAL: additionally store the f32 result to h_out (h-init for the next agg layer).
template <int IN_BF16, int OUT_BF16, int DUAL>
__global__ __launch_bounds__(256, 2)
void k_gemm(const void* __restrict__ in, void* __restrict__ out,
            const float* __restrict__ W, const float* __restrict__ bias,
            float* __restrict__ h_out, int R) {
  __shared__ short Blds[8 * 4 * 64 * 8];  // 32 KiB
  stage_B(W, Blds);
  __syncthreads();
  const int lane = threadIdx.x & 63;
  const int wv = threadIdx.x >> 6;
  const int tiles = R >> 4;
  const int nw = (gridDim.x * blockDim.x) >> 6;
  for (int t = blockIdx.x * (blockDim.x >> 6) + wv; t < tiles; t += nw) {
    const int arow = (t << 4) + (lane & 15);
    bf16x8 a[4];
    if (IN_BF16) {
      const short* ib = (const short*)in;
#pragma unroll
      for (int kc = 0; kc < 4; ++kc)
        a[kc] = *(const bf16x8*)(ib + (size_t)arow * H + kc * 32 + (lane >> 4) * 8);
    } else {
      const float* iff = (const float*)in;
#pragma unroll
      for (int kc = 0; kc < 4; ++kc) {
        const float* p = iff + (size_t)arow * H + kc * 32 + (lane >> 4) * 8;
#pragma unroll
        for (int j = 0; j < 8; ++j) a[kc][j] = (short)f2bf(p[j]);
      }
    }
    f32x4 acc[8];
#pragma unroll
    for (int ct = 0; ct < 8; ++ct) acc[ct] = (f32x4){0.f, 0.f, 0.f, 0.f};
#pragma unroll
    for (int ct = 0; ct < 8; ++ct)
#pragma unroll
      for (int kc = 0; kc < 4; ++kc) {
        bf16x8 b = *(const bf16x8*)(Blds + ((size_t)((ct << 2) + kc) * 64 + lane) * 8);
        acc[ct] = __builtin_amdgcn_mfma_f32_16x16x32_bf16(a[kc], b, acc[ct], 0, 0, 0);
      }
    const int r0 = (t << 4) + ((lane >> 4) << 2);
    const int cb = lane & 15;
#pragma unroll
    for (int ct = 0; ct < 8; ++ct) {
      int c = (ct << 4) + cb;
      float bv = bias[c];
#pragma unroll
      for (int j = 0; j < 4; ++j) {
        float y = fmaxf(acc[ct][j] + bv, 0.f);
        size_t idx = (size_t)(r0 + j) * H + c;
        if (OUT_BF16) ((unsigned short*)out)[idx] = f2bf(y);
        else ((float*)out)[idx] = y;
        if (DUAL) h_out[idx] = y;
      }
    }
  }
}

// ---------------- fused GINE aggregation: h[dst] += relu(x[src] + z2p@We + be) ----------------
__global__ __launch_bounds__(256, 2)
void k_agg_mfma(const unsigned short* __restrict__ x,
                const unsigned short* __restrict__ z2p,
                const float* __restrict__ We, const float* __restrict__ be,
                const int* __restrict__ srcp, const int* __restrict__ dstp,
                float* __restrict__ h, int E) {
  __shared__ short Blds[8 * 4 * 64 * 8];
  __shared__ float s_be[H];
  stage_B(We, Blds);
  for (int i = threadIdx.x; i < H; i += blockDim.x) s_be[i] = be[i];
  __syncthreads();
  const int lane = threadIdx.x & 63;
  const int wv = threadIdx.x >> 6;
  const int cb = lane & 15;
  const int g = lane >> 4;
  const int tiles = E >> 4;
  int t0, t1;
  tile_range(tiles, wv, t0, t1);
  for (int t = t0; t < t1; ++t) {
    const int arow = (t << 4) + cb;
    bf16x8 a[4];
#pragma unroll
    for (int kc = 0; kc < 4; ++kc)
      a[kc] = *(const bf16x8*)((const short*)z2p + (size_t)arow * H + kc * 32 + g * 8);
    f32x4 acc[8];
#pragma unroll
    for (int ct = 0; ct < 8; ++ct) acc[ct] = (f32x4){0.f, 0.f, 0.f, 0.f};
#pragma unroll
    for (int ct = 0; ct < 8; ++ct)
#pragma unroll
      for (int kc = 0; kc < 4; ++kc) {
        bf16x8 b = *(const bf16x8*)(Blds + ((size_t)((ct << 2) + kc) * 64 + lane) * 8);
        acc[ct] = __builtin_amdgcn_mfma_f32_16x16x32_bf16(a[kc], b, acc[ct], 0, 0, 0);
      }
    const int r0 = (t << 4) + (g << 2);
    int sn[4];
#pragma unroll
    for (int j = 0; j < 4; ++j) sn[j] = srcp[r0 + j];
    const int dlo = dstp[t << 4], dhi = dstp[(t << 4) + 15];
    if (dlo == dhi) {  // whole tile -> one node (wave-uniform)
#pragma unroll
      for (int ct = 0; ct < 8; ++ct) {
        int c = (ct << 4) + cb;
        float bv = s_be[c];
        float run = 0.f;
#pragma unroll
        for (int j = 0; j < 4; ++j) {
          float xv = bf2f(x[(size_t)sn[j] * H + c]);
          run += fmaxf(0.f, xv + acc[ct][j] + bv);
        }
        run += __shfl_xor(run, 16);
        run += __shfl_xor(run, 32);
        if (g == 0) atomicAdd(h + (size_t)dlo * H + c, run);
      }
    } else {
      int dn[4];
#pragma unroll
      for (int j = 0; j < 4; ++j) dn[j] = dstp[r0 + j];
#pragma unroll
      for (int ct = 0; ct < 8; ++ct) {
        int c = (ct << 4) + cb;
        float bv = s_be[c];
        float run = 0.f;
        int prev = dn[0];
#pragma unroll
        for (int j = 0; j < 4; ++j) {
          float xv = bf2f(x[(size_t)sn[j] * H + c]);
          float msg = fmaxf(0.f, xv + acc[ct][j] + bv);
          if (dn[j] != prev) {
            atomicAdd(h + (size_t)prev * H + c, run);
            run = 0.f;
            prev = dn[j];
          }
          run += msg;
        }
        atomicAdd(h + (size_t)prev * H + c, run);
      }
    }
  }
}

// ---------------- conv1 first MLP (rank-1): x[n][c] = relu((1+h1[n])*W1a[c] + b1a[c]) ------
__global__ void k_c1a(const float* __restrict__ h1, const float* __restrict__ W1a,
                      const float* __restrict__ b1a, unsigned short* __restrict__ x, int N) {
  int idx = blockIdx.x * blockDim.x + threadIdx.x;
  int n = idx >> 6;
  if (n >= N) return;
  int c0 = (idx & 63) * 2;
  float hv = 1.0f + h1[n];
  float y0 = fmaxf(0.f, fmaf(hv, W1a[c0], b1a[c0]));
  float y1 = fmaxf(0.f, fmaf(hv, W1a[c0 + 1], b1a[c0 + 1]));
  unsigned int pack = ((unsigned int)f2bf(y1) << 16) | f2bf(y0);
  *(unsigned int*)(x + (size_t)n * H + c0) = pack;
}

// ---------------- pool ----------------
__global__ void k_pool(const unsigned short* __restrict__ x, const int* __restrict__ batch,
                       float* __restrict__ g, int N, int G) {
  __shared__ float red[4][H];
  int gi = blockIdx.x;
  int lane = threadIdx.x & 63;
  int w = threadIdx.x >> 6;
  int lo = lb(batch, N, gi), hi = lb(batch, N, gi + 1);
  float a0 = 0.f, a1 = 0.f;
  for (int n = lo + w; n < hi; n += 4) {
    unsigned int pk = *(const unsigned int*)(x + (size_t)n * H + lane * 2);
    a0 += bf2f(pk & 0xffffu);
    a1 += bf2f(pk >> 16);
  }
  red[w][2 * lane] = a0;
  red[w][2 * lane + 1] = a1;
  __syncthreads();
  if (w == 0) {
    a0 = red[0][2 * lane] + red[1][2 * lane] + red[2][2 * lane] + red[3][2 * lane];
    a1 = red[0][2 * lane + 1] + red[1][2 * lane + 1] + red[2][2 * lane + 1] + red[3][2 * lane + 1];
    *(float2*)(g + (size_t)gi * H + 2 * lane) = make_float2(a0, a1);
  }
}

// ---------------- head ----------------
__global__ void k_head(const float* __restrict__ g, const float* __restrict__ Wl1,
                       const float* __restrict__ bl1, const float* __restrict__ Wl2,
                       const float* __restrict__ bl2, float* __restrict__ out, int G) {
  int gi = blockIdx.x;
  int lane = threadIdx.x & 63;
  const int c0 = 2 * lane, c1 = c0 + 1;
  float2 gv = *(const float2*)(g + (size_t)gi * H + c0);
  float m0 = bl1[c0], m1 = bl1[c1];
#pragma unroll
  for (int k = 0; k < H; ++k) {
    float s = __shfl((k & 1) ? gv.y : gv.x, k >> 1);
    float2 w = *(const float2*)(Wl1 + k * H + c0);
    m0 = fmaf(s, w.x, m0);
    m1 = fmaf(s, w.y, m1);
  }
  float t0 = fmaxf(0.f, m0), t1 = fmaxf(0.f, m1);
  float L0 = bl2[c0], L1 = bl2[c1];
#pragma unroll
  for (int k = 0; k < H; ++k) {
    float s = __shfl((k & 1) ? t1 : t0, k >> 1);
    float2 w = *(const float2*)(Wl2 + k * H + c0);
    L0 = fmaf(s, w.x, L0);
    L1 = fmaf(s, w.y, L1);
  }
  float mx = wave_max(fmaxf(L0, L1));
  float sm = wave_sum(expf(L0 - mx) + expf(L1 - mx));
  float lse = mx + logf(sm);
  *(float2*)(out + (size_t)gi * H + c0) = make_float2(L0 - lse, L1 - lse);
}

__global__ void k_zero_out(float* __restrict__ out, int n) {
  int i = blockIdx.x * blockDim.x + threadIdx.x;
  if (i < n) out[i] = 0.f;
}

extern "C" void kernel_launch(void* const* d_in, const int* in_sizes, int n_in,
                              void* d_out, int out_size, void* d_ws, size_t ws_size,
                              hipStream_t stream) {
  const int* edge_index = (const int*)d_in[0];
  const int* batch = (const int*)d_in[1];
  const int* pos_index = (const int*)d_in[2];
  const float* pos_enc = (const float*)d_in[3];
  const int* pos_batch = (const int*)d_in[4];
  const float* z_table = (const float*)d_in[5];
  const float* bn1_g = (const float*)d_in[6];
  const float* bn1_b = (const float*)d_in[7];
  const float* Wz = (const float*)d_in[8];
  const float* bz = (const float*)d_in[9];
  const float* bn2_g = (const float*)d_in[10];
  const float* bn2_b = (const float*)d_in[11];
  const float* We1 = (const float*)d_in[12];
  const float* be1 = (const float*)d_in[13];
  const float* W1a = (const float*)d_in[14];
  const float* b1a = (const float*)d_in[15];
  const float* W1b = (const float*)d_in[16];
  const float* b1b = (const float*)d_in[17];
  const float* We = (const float*)d_in[18];
  const float* be = (const float*)d_in[19];
  const float* Wa = (const float*)d_in[20];
  const float* ba = (const float*)d_in[21];
  const float* Wb = (const float*)d_in[22];
  const float* bb = (const float*)d_in[23];
  const float* Wl1 = (const float*)d_in[24];
  const float* bl1 = (const float*)d_in[25];
  const float* Wl2 = (const float*)d_in[26];
  const float* bl2 = (const float*)d_in[27];

  const int E = in_sizes[0] / 2;
  const int N = in_sizes[1];
  const int P = in_sizes[2];
  const int L = in_sizes[18] / (H * H);
  const int G = out_size / H;
  const int* src = edge_index;
  const int* dst = edge_index + E;

  char* wsb = (char*)d_ws;
  size_t o = 0;
  auto alloc = [&](size_t bytes) -> void* {
    o = (o + 255) & ~(size_t)255;
    void* p = wsb + o;
    o += bytes;
    return p;
  };
  unsigned short* z2p = (unsigned short*)alloc((size_t)E * H * 2);  // 204.8 MB, CSR-permuted
  unsigned short* x = (unsigned short*)alloc((size_t)N * H * 2);    // 12.8 MB
  float* h = (float*)alloc((size_t)N * H * 4);                      // 25.6 MB
  float* h1 = (float*)alloc((size_t)N * 4);
  int* cnt = (int*)alloc((size_t)N * 4);
  int* off = (int*)alloc((size_t)(N + 1) * 4);
  int* cur = (int*)alloc((size_t)N * 4);
  int* srcp = (int*)alloc((size_t)E * 4);  // holds eids first, then src[eids] in place
  int* dstp = (int*)alloc((size_t)E * 4);
  int* pos_off = (int*)alloc((size_t)(E + 1) * 4);
  float* g = (float*)alloc((size_t)G * H * 4);
  (void)n_in;

  if (o > ws_size) {  // fail fast instead of OOB queue hang
    k_zero_out<<<(out_size + 255) / 256, 256, 0, stream>>>((float*)d_out, out_size);
    return;
  }

  hipMemsetAsync(cnt, 0, (size_t)N * 4, stream);
  hipMemsetAsync(h1, 0, (size_t)N * 4, stream);

  // CSR + permutation metadata
  k_count<<<(E + 255) / 256, 256, 0, stream>>>(dst, cnt, E);
  k_scan<<<1, 1024, 0, stream>>>(cnt, off, cur, N);
  k_scatter<<<(E + 255) / 256, 256, 0, stream>>>(dst, cur, srcp /*eids*/, E);
  k_dstp<<<(N + 255) / 256, 256, 0, stream>>>(off, dstp, N);
  k_posoff<<<(P + 255) / 256, 256, 0, stream>>>(pos_batch, pos_off, P, E);

  // fused edge embedding (za + GEMM(Wz) + msg1)
  k_zfused<<<2048, 256, 0, stream>>>(srcp /*eids*/, pos_off, pos_index, pos_enc, z_table,
                                     bn1_g, bn1_b, Wz, bz, bn2_g, bn2_b, We1, be1, dstp, h1,
                                     z2p, E);
  k_srcp<<<(E + 255) / 256, 256, 0, stream>>>(src, srcp, E);  // eids -> src[eids] in place

  // conv1
  k_c1a<<<(N * 64 + 255) / 256, 256, 0, stream>>>(h1, W1a, b1a, x, N);
  k_gemm<1, 1, 1><<<782, 256, 0, stream>>>(x, x, W1b, b1b, h, N);  // x bf16 + h=x f32

  // GINE layers
  for (int l = 0; l < L; ++l) {
    k_agg_mfma<<<2048, 256, 0, stream>>>(x, z2p, We + (size_t)l * H * H, be + (size_t)l * H,
                                         srcp, dstp, h, E);
    k_gemm<0, 0, 0><<<782, 256, 0, stream>>>(h, h, Wa + (size_t)l * H * H, ba + (size_t)l * H,
                                             nullptr, N);
    if (l < L - 1)
      k_gemm<0, 1, 1><<<782, 256, 0, stream>>>(h, x, Wb + (size_t)l * H * H, bb + (size_t)l * H,
                                               h, N);  // x bf16 + h=x f32 for next layer
    else
      k_gemm<0, 1, 0><<<782, 256, 0, stream>>>(h, x, Wb + (size_t)l * H * H, bb + (size_t)l * H,
                                               nullptr, N);
  }

  k_pool<<<G, 256, 0, stream>>>(x, batch, g, N, G);
  k_head<<<G, 64, 0, stream>>>(g, Wl1, bl1, Wl2, bl2, (float*)d_out, G);
}